// Round 6
// baseline (1685.311 us; speedup 1.0000x reference)
//
#include <hip/hip_runtime.h>
#include <hip/hip_bf16.h>
#include <cstdint>

// ---------------------------------------------------------------------------
// ThreeLayerCNN (BranchyNet early-exit), B=4096.
// Precision: conv1/conv2/exit1/exit2 fp32 (argmax parity with numpy ref);
// big FC GEMMs (l1c1, l1c2) bf16 MFMA w/ fp32 accum (output tol 0.146).
// Round 6: conv2 = block-per-image (r4 data path) with 2oc x 5pos register
// blocking: patch strip read as ds_read_b128 (12/ic) reused for 10 outputs,
// weights (stride-13, <=2-way banks) 18 b32/ic. LDS insts per wave-ic
// 244 -> 30. FP expression tree identical to r4 (exit2 parity).
// ---------------------------------------------------------------------------

typedef __bf16 bf16_t;
typedef __bf16 bf16x8 __attribute__((ext_vector_type(8)));
typedef float  f32x4  __attribute__((ext_vector_type(4)));

#define B_IMG 4096

// ---------------------------------------------------------------------------
// conv1 (1->50, 3x3) + relu + maxpool2.  x:[nimg,1,28,28] -> h1:[nimg,8480]
// ---------------------------------------------------------------------------
__global__ __launch_bounds__(256) void conv1_pool(
    const float* __restrict__ x, const float* __restrict__ w1,
    const float* __restrict__ b1, float* __restrict__ h1, int nimg)
{
    __shared__ float ws[450];
    __shared__ float bs[50];
    const int t = threadIdx.x;
    for (int i = t; i < 450; i += 256) ws[i] = w1[i];
    if (t < 50) bs[t] = b1[t];
    __syncthreads();

    const int idx = blockIdx.x * 256 + t;
    if (idx >= nimg * 169) return;
    const int b   = idx / 169;
    const int pos = idx % 169;
    const int py = pos / 13, px = pos % 13;

    const float* xp = x + (size_t)b * 784 + (2 * py) * 28 + 2 * px;
    float p[4][4];
#pragma unroll
    for (int r = 0; r < 4; ++r)
#pragma unroll
        for (int c = 0; c < 4; ++c) p[r][c] = xp[r * 28 + c];

    float* hb = h1 + (size_t)b * 8480 + pos;
    if (pos < 30) h1[(size_t)b * 8480 + 8450 + pos] = 0.f;   // zero pad cols

    for (int oc = 0; oc < 50; ++oc) {
        const float* wp = &ws[oc * 9];
        const float w00 = wp[0], w01 = wp[1], w02 = wp[2];
        const float w10 = wp[3], w11 = wp[4], w12 = wp[5];
        const float w20 = wp[6], w21 = wp[7], w22 = wp[8];
        float a[2][2];
#pragma unroll
        for (int dy = 0; dy < 2; ++dy)
#pragma unroll
            for (int dx = 0; dx < 2; ++dx) {
                a[dy][dx] = p[dy + 0][dx + 0] * w00 + p[dy + 0][dx + 1] * w01 + p[dy + 0][dx + 2] * w02
                          + p[dy + 1][dx + 0] * w10 + p[dy + 1][dx + 1] * w11 + p[dy + 1][dx + 2] * w12
                          + p[dy + 2][dx + 0] * w20 + p[dy + 2][dx + 1] * w21 + p[dy + 2][dx + 2] * w22;
            }
        float v = fmaxf(fmaxf(a[0][0], a[0][1]), fmaxf(a[1][0], a[1][1])) + bs[oc];
        hb[oc * 169] = fmaxf(v, 0.f);
    }
}

// ---------------------------------------------------------------------------
// conv2 (50->50) + relu + pool. h1:[nimg,8480] -> h2:[nimg,1280] (pads zeroed)
// Block = 1 img, 128 threads (125 active = 25 ocg(2oc) x 5 prow).
// Input staged [ic][row*20+col] (b128-aligned, prow banks spread); weights
// double-buffered 5-ic chunks, stride 13. Per thread-ic: 12 b128 patch reads
// reused for 2oc x 5px x 4sub = 40 outputs (360 FMA) + 18 b32 weight reads.
// FP expression per output identical to r4 (exit2 argmax parity).
// ---------------------------------------------------------------------------
__global__ __launch_bounds__(128) void conv2_tile(
    const float* __restrict__ h1, const float* __restrict__ w2,
    const float* __restrict__ b2, float* __restrict__ h2)
{
    __shared__ float in[50 * 260];       // [ic][row*20 + col], 13 rows x 13 cols
    __shared__ float wbuf[2][5 * 650];   // [buf][icl*650 + oc*13 + j]
    const int b = blockIdx.x;
    const int t = threadIdx.x;

    // stage input image (coalesced global, scattered-but-cheap LDS writes)
    for (int i = t; i < 8450; i += 128) {
        const int ic = i / 169, rr = i - ic * 169;
        const int row = rr / 13, col = rr - row * 13;
        in[ic * 260 + row * 20 + col] = h1[(size_t)b * 8480 + i];
    }
    // stage first weight chunk (ic 0..4)
    for (int s = t; s < 3250; s += 128) {
        const int icl = s / 650, r = s - icl * 650;
        const int oc = r / 13, j = r - oc * 13;
        wbuf[0][s] = (j < 9) ? w2[oc * 450 + icl * 9 + j] : 0.f;
    }
    __syncthreads();

    if (t < 30) h2[(size_t)b * 1280 + 1250 + t] = 0.f;   // zero pad cols

    const int tt   = (t < 125) ? t : 0;
    const int ocg  = tt / 5;          // 0..24
    const int prow = tt % 5;          // 0..4
    const int oc0  = ocg * 2;
    const bool act = (t < 125);

    float acc[2][5][4];               // [oc][px][dy*2+dx]
#pragma unroll
    for (int o = 0; o < 2; ++o)
#pragma unroll
        for (int x5 = 0; x5 < 5; ++x5)
#pragma unroll
            for (int q = 0; q < 4; ++q) acc[o][x5][q] = 0.f;

    for (int ic0 = 0; ic0 < 50; ic0 += 5) {
        const int cur = (ic0 / 5) & 1;
        if (ic0 + 5 < 50) {           // prefetch next 5-ic weight chunk
            const int nxt = cur ^ 1;
            for (int s = t; s < 3250; s += 128) {
                const int icl = s / 650, r = s - icl * 650;
                const int oc = r / 13, j = r - oc * 13;
                wbuf[nxt][s] = (j < 9) ? w2[oc * 450 + (ic0 + 5 + icl) * 9 + j] : 0.f;
            }
        }
        if (act) {
#pragma unroll
            for (int icl = 0; icl < 5; ++icl) {
                const float* ip = &in[(ic0 + icl) * 260 + (2 * prow) * 20];
                f32x4 pr[4][3];
#pragma unroll
                for (int r = 0; r < 4; ++r)
#pragma unroll
                    for (int c3 = 0; c3 < 3; ++c3)
                        pr[r][c3] = *(const f32x4*)&ip[r * 20 + c3 * 4];
                const float* wl = &wbuf[cur][icl * 650 + oc0 * 13];
#pragma unroll
                for (int oi = 0; oi < 2; ++oi) {
                    const float* wp = wl + oi * 13;
                    const float w00 = wp[0], w01 = wp[1], w02 = wp[2];
                    const float w10 = wp[3], w11 = wp[4], w12 = wp[5];
                    const float w20 = wp[6], w21 = wp[7], w22 = wp[8];
#pragma unroll
                    for (int px = 0; px < 5; ++px) {
#pragma unroll
                        for (int dy = 0; dy < 2; ++dy) {
#pragma unroll
                            for (int dx = 0; dx < 2; ++dx) {
                                // P(r,c) with c = 2*px+dx+kx (compile-time)
#define PAT(r_, c_) (pr[r_][(c_) >> 2][(c_) & 3])
                                acc[oi][px][dy * 2 + dx] +=
                                      PAT(dy + 0, 2 * px + dx + 0) * w00 + PAT(dy + 0, 2 * px + dx + 1) * w01 + PAT(dy + 0, 2 * px + dx + 2) * w02
                                    + PAT(dy + 1, 2 * px + dx + 0) * w10 + PAT(dy + 1, 2 * px + dx + 1) * w11 + PAT(dy + 1, 2 * px + dx + 2) * w12
                                    + PAT(dy + 2, 2 * px + dx + 0) * w20 + PAT(dy + 2, 2 * px + dx + 1) * w21 + PAT(dy + 2, 2 * px + dx + 2) * w22;
#undef PAT
                            }
                        }
                    }
                }
            }
        }
        __syncthreads();
    }

    if (act) {
#pragma unroll
        for (int oi = 0; oi < 2; ++oi) {
            const float bv = b2[oc0 + oi];
#pragma unroll
            for (int px = 0; px < 5; ++px) {
                float v = fmaxf(fmaxf(acc[oi][px][0], acc[oi][px][1]),
                                fmaxf(acc[oi][px][2], acc[oi][px][3]));
                v = fmaxf(v + bv, 0.f);
                h2[(size_t)b * 1280 + (oc0 + oi) * 25 + prow * 5 + px] = v;
            }
        }
    }
}

// ---------------------------------------------------------------------------
// conv3 (50->50 on 5x5) + relu + pool -> f3:[nimg,50]. 4 images per block.
// ---------------------------------------------------------------------------
__global__ __launch_bounds__(256) void conv3_pool(
    const float* __restrict__ h2, const float* __restrict__ w3,
    const float* __restrict__ b3, float* __restrict__ f3)
{
    __shared__ float in[5000];
    const int blk = blockIdx.x;
    const int t = threadIdx.x;
    for (int i = t; i < 5000; i += 256) {
        const int img = i / 1250, off = i % 1250;
        in[i] = h2[(size_t)(blk * 4 + img) * 1280 + off];
    }
    __syncthreads();
    const int il = t >> 6;
    const int oc = t & 63;
    if (oc >= 50) return;

    const float* ip0 = &in[il * 1250];
    float a00 = 0.f, a01 = 0.f, a10 = 0.f, a11 = 0.f;
    for (int ic = 0; ic < 50; ++ic) {
        float p[4][4];
        const float* ip = ip0 + ic * 25;
#pragma unroll
        for (int r = 0; r < 4; ++r)
#pragma unroll
            for (int c = 0; c < 4; ++c) p[r][c] = ip[r * 5 + c];
        const float* wp = &w3[((size_t)oc * 50 + ic) * 9];
        const float w00 = wp[0], w01 = wp[1], w02 = wp[2];
        const float w10 = wp[3], w11 = wp[4], w12 = wp[5];
        const float w20 = wp[6], w21 = wp[7], w22 = wp[8];
        a00 += p[0][0]*w00 + p[0][1]*w01 + p[0][2]*w02 + p[1][0]*w10 + p[1][1]*w11 + p[1][2]*w12 + p[2][0]*w20 + p[2][1]*w21 + p[2][2]*w22;
        a01 += p[0][1]*w00 + p[0][2]*w01 + p[0][3]*w02 + p[1][1]*w10 + p[1][2]*w11 + p[1][3]*w12 + p[2][1]*w20 + p[2][2]*w21 + p[2][3]*w22;
        a10 += p[1][0]*w00 + p[1][1]*w01 + p[1][2]*w02 + p[2][0]*w10 + p[2][1]*w11 + p[2][2]*w12 + p[3][0]*w20 + p[3][1]*w21 + p[3][2]*w22;
        a11 += p[1][1]*w00 + p[1][2]*w01 + p[1][3]*w02 + p[2][1]*w10 + p[2][2]*w11 + p[2][3]*w12 + p[3][1]*w20 + p[3][2]*w21 + p[3][3]*w22;
    }
    float v = fmaxf(fmaxf(a00, a01), fmaxf(a10, a11)) + b3[oc];
    f3[(size_t)(blk * 4 + il) * 50 + oc] = fmaxf(v, 0.f);
}

// ---------------------------------------------------------------------------
// exit: z = f @ dw^T + db (2 outputs); e[b] = (z0 >= z1). fp32, block/sample.
// ---------------------------------------------------------------------------
__global__ __launch_bounds__(256) void exit_kernel(
    const float* __restrict__ F, int ldf, int K,
    const float* __restrict__ dw, const float* __restrict__ db, int* __restrict__ e)
{
    const int b = blockIdx.x;
    const int t = threadIdx.x;
    const float* f = F + (size_t)b * ldf;
    float s0 = 0.f, s1 = 0.f;
    for (int i = t; i < K; i += 256) {
        const float v = f[i];
        s0 += v * dw[i];
        s1 += v * dw[K + i];
    }
    __shared__ float r0[256];
    __shared__ float r1[256];
    r0[t] = s0; r1[t] = s1;
    __syncthreads();
    for (int s = 128; s > 0; s >>= 1) {
        if (t < s) { r0[t] += r0[t + s]; r1[t] += r1[t + s]; }
        __syncthreads();
    }
    if (t == 0) e[b] = (r0[0] + db[0] >= r1[0] + db[1]) ? 1 : 0;
}

// ---------------------------------------------------------------------------
// fp32 [N,K] -> bf16 [Np,Kp], zero-padded.
// ---------------------------------------------------------------------------
__global__ __launch_bounds__(256) void w_to_bf16(
    const float* __restrict__ src, bf16_t* __restrict__ dst, int N, int K, int Kp, int total)
{
    const int idx = blockIdx.x * 256 + threadIdx.x;
    if (idx >= total) return;
    const int n = idx / Kp, k = idx % Kp;
    const float v = (n < N && k < K) ? src[(size_t)n * K + k] : 0.f;
    dst[idx] = (bf16_t)v;
}

// ---------------------------------------------------------------------------
// MFMA GEMM: C[M,ldc] = bf16(A_f32[M,lda]) @ W_bf16[Np,Kp]^T + bias
// BM=128, BN=64, BK=32. LDS row stride 40.
// ---------------------------------------------------------------------------
__global__ __launch_bounds__(256) void gemm_f32a_bf16w(
    const float* __restrict__ A, int lda,
    const bf16_t* __restrict__ W,
    const float* __restrict__ bias, float* __restrict__ C,
    int Kp, int Nout, int ldc)
{
    __shared__ __align__(16) bf16_t As[128 * 40];
    __shared__ __align__(16) bf16_t Bs[64 * 40];

    const int t = threadIdx.x;
    const int m0 = blockIdx.x * 128;
    const int n0 = blockIdx.y * 64;
    const int wave = t >> 6;
    const int lane = t & 63;
    const int wm = (wave >> 1) * 64;
    const int wn = (wave & 1) * 32;
    const int quad = lane >> 4;
    const int lr = lane & 15;

    f32x4 acc[4][2];
#pragma unroll
    for (int i = 0; i < 4; ++i)
#pragma unroll
        for (int j = 0; j < 2; ++j) acc[i][j] = (f32x4)0.f;

    const int ar = t >> 2;          // 0..63
    const int ac = (t & 3) * 8;     // 0,8,16,24

    for (int k0 = 0; k0 < Kp; k0 += 32) {
        __syncthreads();
#pragma unroll
        for (int h = 0; h < 2; ++h) {
            const float* ap = A + (size_t)(m0 + ar + h * 64) * lda + k0 + ac;
            const float4 f0 = *(const float4*)ap;
            const float4 f1 = *(const float4*)(ap + 4);
            bf16x8 v;
            v[0] = (bf16_t)f0.x; v[1] = (bf16_t)f0.y; v[2] = (bf16_t)f0.z; v[3] = (bf16_t)f0.w;
            v[4] = (bf16_t)f1.x; v[5] = (bf16_t)f1.y; v[6] = (bf16_t)f1.z; v[7] = (bf16_t)f1.w;
            *(bf16x8*)&As[(ar + h * 64) * 40 + ac] = v;
        }
        *(uint4*)&Bs[ar * 40 + ac] = *(const uint4*)&W[(size_t)(n0 + ar) * Kp + k0 + ac];
        __syncthreads();

        bf16x8 af[4], bfr[2];
#pragma unroll
        for (int i = 0; i < 4; ++i)
            af[i] = *(const bf16x8*)&As[(wm + i * 16 + lr) * 40 + quad * 8];
#pragma unroll
        for (int j = 0; j < 2; ++j)
            bfr[j] = *(const bf16x8*)&Bs[(wn + j * 16 + lr) * 40 + quad * 8];
#pragma unroll
        for (int i = 0; i < 4; ++i)
#pragma unroll
            for (int j = 0; j < 2; ++j)
                acc[i][j] = __builtin_amdgcn_mfma_f32_16x16x32_bf16(af[i], bfr[j], acc[i][j], 0, 0, 0);
    }

#pragma unroll
    for (int j = 0; j < 2; ++j) {
        const int n = n0 + wn + j * 16 + lr;
        const float bv = (n < Nout) ? bias[n] : 0.f;
#pragma unroll
        for (int i = 0; i < 4; ++i) {
            const int mrow = m0 + wm + i * 16 + quad * 4;
#pragma unroll
            for (int r = 0; r < 4; ++r)
                C[(size_t)(mrow + r) * ldc + n] = acc[i][j][r] + bv;
        }
    }
}

// ---------------------------------------------------------------------------
// out[b,o<10] = U[b,:500] @ W[o,:500] + bias[o].
// Block: 256 thr = 16 images x 16 k-strips (lane-adjacent = k, coalesced).
// ---------------------------------------------------------------------------
__global__ __launch_bounds__(256) void lin10(
    const float* __restrict__ U, int ldu,
    const float* __restrict__ W, const float* __restrict__ bias,
    float* __restrict__ out)
{
    __shared__ float red[16][10][17];
    const int t = threadIdx.x;
    const int ks = t & 15;
    const int il = t >> 4;
    const int b  = blockIdx.x * 16 + il;
    const float* u = U + (size_t)b * ldu;

    float acc[10];
#pragma unroll
    for (int o = 0; o < 10; ++o) acc[o] = 0.f;

    for (int i = 0; i < 31; ++i) {
        const int k = ks + i * 16;          // <= 495
        const float uv = u[k];
#pragma unroll
        for (int o = 0; o < 10; ++o) acc[o] += uv * W[o * 500 + k];
    }
    {   // tail: k = 496..511, valid only k<500
        const int k = ks + 496;
        if (k < 500) {
            const float uv = u[k];
#pragma unroll
            for (int o = 0; o < 10; ++o) acc[o] += uv * W[o * 500 + k];
        }
    }
#pragma unroll
    for (int o = 0; o < 10; ++o) red[il][o][ks] = acc[o];
    __syncthreads();
    if (t < 160) {
        const int il2 = t / 10, o = t - il2 * 10;
        float s = 0.f;
#pragma unroll
        for (int q = 0; q < 16; ++q) s += red[il2][o][q];
        out[(size_t)(blockIdx.x * 16 + il2) * 10 + o] = s + bias[o];
    }
}

// ---------------------------------------------------------------------------
// u3[b,o<500] = relu(f3[b,:50] @ l1w[o,:50] + l1b[o]); u3 row stride 512.
// ---------------------------------------------------------------------------
__global__ __launch_bounds__(256) void lin500(
    const float* __restrict__ f3, const float* __restrict__ w,
    const float* __restrict__ bias, float* __restrict__ u3)
{
    __shared__ float fs[50];
    const int b = blockIdx.x;
    const int t = threadIdx.x;
    if (t < 50) fs[t] = f3[(size_t)b * 50 + t];
    __syncthreads();
    for (int o = t; o < 500; o += 256) {
        float s = 0.f;
#pragma unroll
        for (int k = 0; k < 50; ++k) s += fs[k] * w[o * 50 + k];
        u3[(size_t)b * 512 + o] = fmaxf(s + bias[o], 0.f);
    }
}

// ---------------------------------------------------------------------------
// select per exits, log_softmax over 10, write final output (full batch).
// ---------------------------------------------------------------------------
__global__ __launch_bounds__(256) void final_select(
    const int* __restrict__ e1, const int* __restrict__ e2,
    const float* __restrict__ o1, const float* __restrict__ o2,
    const float* __restrict__ o3, float* __restrict__ out)
{
    const int b = blockIdx.x * 256 + threadIdx.x;
    if (b >= B_IMG) return;
    const float* src = e1[b] ? o1 : (e2[b] ? o2 : o3);
    src += (size_t)b * 10;
    float v[10];
    float m = -3.4e38f;
#pragma unroll
    for (int o = 0; o < 10; ++o) { v[o] = src[o]; m = fmaxf(m, v[o]); }
    float s = 0.f;
#pragma unroll
    for (int o = 0; o < 10; ++o) s += expf(v[o] - m);
    const float ls = logf(s);
#pragma unroll
    for (int o = 0; o < 10; ++o) out[(size_t)b * 10 + o] = v[o] - m - ls;
}

// ---------------------------------------------------------------------------
static inline size_t align256(size_t v) { return (v + 255) & ~(size_t)255; }

extern "C" void kernel_launch(void* const* d_in, const int* in_sizes, int n_in,
                              void* d_out, int out_size, void* d_ws, size_t ws_size,
                              hipStream_t stream)
{
    const float* x     = (const float*)d_in[0];
    const float* c1w   = (const float*)d_in[1];
    const float* c1b   = (const float*)d_in[2];
    const float* c2w   = (const float*)d_in[3];
    const float* c2b   = (const float*)d_in[4];
    const float* c3w   = (const float*)d_in[5];
    const float* c3b   = (const float*)d_in[6];
    const float* l1c1w = (const float*)d_in[7];
    const float* l1c1b = (const float*)d_in[8];
    const float* l2c1w = (const float*)d_in[9];
    const float* l2c1b = (const float*)d_in[10];
    const float* l1c2w = (const float*)d_in[11];
    const float* l1c2b = (const float*)d_in[12];
    const float* l2c2w = (const float*)d_in[13];
    const float* l2c2b = (const float*)d_in[14];
    const float* l1w   = (const float*)d_in[15];
    const float* l1b   = (const float*)d_in[16];
    const float* l2w   = (const float*)d_in[17];
    const float* l2b   = (const float*)d_in[18];
    const float* d1w   = (const float*)d_in[19];
    const float* d1b   = (const float*)d_in[20];
    const float* d2w   = (const float*)d_in[21];
    const float* d2b   = (const float*)d_in[22];

    // ---- persistent layout (full batch) ----
    size_t off = 0;
    const size_t oWb1  = off; off = align256(off + (size_t)512 * 8480 * 2);
    const size_t oWb2  = off; off = align256(off + (size_t)512 * 1280 * 2);
    const size_t oOut1 = off; off = align256(off + (size_t)B_IMG * 10 * 4);
    const size_t oOut2 = off; off = align256(off + (size_t)B_IMG * 10 * 4);
    const size_t oOut3 = off; off = align256(off + (size_t)B_IMG * 10 * 4);
    const size_t oE1   = off; off = align256(off + (size_t)B_IMG * 4);
    const size_t oE2   = off; off = align256(off + (size_t)B_IMG * 4);
    const size_t persist = off;

    // ---- per-chunk bytes: h1 + h2 + u(shared) + f3 ----
    auto chunk_bytes = [](int C) {
        size_t s = 0;
        s += align256((size_t)C * 8480 * 4);   // h1
        s += align256((size_t)C * 1280 * 4);   // h2
        s += align256((size_t)C * 512 * 4);    // u (shared across stages)
        s += align256((size_t)C * 50 * 4);     // f3
        return s;
    };
    int C = B_IMG;
    while (C > 256 && persist + chunk_bytes(C) > ws_size) C >>= 1;

    char* ws = (char*)d_ws;
    bf16_t* Wb1  = (bf16_t*)(ws + oWb1);
    bf16_t* Wb2  = (bf16_t*)(ws + oWb2);
    float*  out1 = (float*) (ws + oOut1);
    float*  out2 = (float*) (ws + oOut2);
    float*  out3 = (float*) (ws + oOut3);
    int*    e1   = (int*)   (ws + oE1);
    int*    e2   = (int*)   (ws + oE2);

    size_t co = persist;
    float* h1 = (float*)(ws + co); co += align256((size_t)C * 8480 * 4);
    float* h2 = (float*)(ws + co); co += align256((size_t)C * 1280 * 4);
    float* u  = (float*)(ws + co); co += align256((size_t)C * 512 * 4);
    float* f3 = (float*)(ws + co); co += align256((size_t)C * 50 * 4);

    float* out = (float*)d_out;

    // weight conversion (once)
    w_to_bf16<<<(512 * 8480) / 256, 256, 0, stream>>>(l1c1w, Wb1, 500, 8450, 8480, 512 * 8480);
    w_to_bf16<<<(512 * 1280) / 256, 256, 0, stream>>>(l1c2w, Wb2, 500, 1250, 1280, 512 * 1280);

    for (int b0 = 0; b0 < B_IMG; b0 += C) {
        // stage 1
        conv1_pool<<<(C * 169 + 255) / 256, 256, 0, stream>>>(x + (size_t)b0 * 784, c1w, c1b, h1, C);
        exit_kernel<<<C, 256, 0, stream>>>(h1, 8480, 8450, d1w, d1b, e1 + b0);
        gemm_f32a_bf16w<<<dim3(C / 128, 8), 256, 0, stream>>>(h1, 8480, Wb1, l1c1b, u, 8480, 500, 512);
        lin10<<<C / 16, 256, 0, stream>>>(u, 512, l2c1w, l2c1b, out1 + (size_t)b0 * 10);

        // stage 2
        conv2_tile<<<C, 128, 0, stream>>>(h1, c2w, c2b, h2);
        exit_kernel<<<C, 256, 0, stream>>>(h2, 1280, 1250, d2w, d2b, e2 + b0);
        gemm_f32a_bf16w<<<dim3(C / 128, 8), 256, 0, stream>>>(h2, 1280, Wb2, l1c2b, u, 1280, 500, 512);
        lin10<<<C / 16, 256, 0, stream>>>(u, 512, l2c2w, l2c2b, out2 + (size_t)b0 * 10);

        // stage 3
        conv3_pool<<<C / 4, 256, 0, stream>>>(h2, c3w, c3b, f3);
        lin500<<<C, 256, 0, stream>>>(f3, l1w, l1b, u);
        lin10<<<C / 16, 256, 0, stream>>>(u, 512, l2w, l2b, out3 + (size_t)b0 * 10);
    }

    final_select<<<B_IMG / 256, 256, 0, stream>>>(e1, e2, out1, out2, out3, out);

    (void)in_sizes; (void)n_in; (void)out_size; (void)ws_size;
}

// Round 7
// 1274.727 us; speedup vs baseline: 1.3221x; 1.3221x over previous
//
#include <hip/hip_runtime.h>
#include <hip/hip_bf16.h>
#include <cstdint>

// ---------------------------------------------------------------------------
// ThreeLayerCNN (BranchyNet early-exit), B=4096.
// Precision: conv1/conv2/exit1/exit2 fp32 (argmax parity with numpy ref);
// big FC GEMMs (l1c1, l1c2) bf16 MFMA w/ fp32 accum (output tol 0.146).
// Round 7: conv2 = 2-img block, lane=(img,pos), wave=13-oc slice with
// WAVE-UNIFORM scalar weight loads (s_load pipe, free), patches from LDS
// (16 b32/thread/ic), no barrier in ic loop. VALU-bound by ~6x.
// FP expression tree identical to r2/r4 (exit2 argmax parity).
// ---------------------------------------------------------------------------

typedef __bf16 bf16_t;
typedef __bf16 bf16x8 __attribute__((ext_vector_type(8)));
typedef float  f32x4  __attribute__((ext_vector_type(4)));

#define B_IMG 4096

// ---------------------------------------------------------------------------
// conv1 (1->50, 3x3) + relu + maxpool2.  x:[nimg,1,28,28] -> h1:[nimg,8480]
// ---------------------------------------------------------------------------
__global__ __launch_bounds__(256) void conv1_pool(
    const float* __restrict__ x, const float* __restrict__ w1,
    const float* __restrict__ b1, float* __restrict__ h1, int nimg)
{
    __shared__ float ws[450];
    __shared__ float bs[50];
    const int t = threadIdx.x;
    for (int i = t; i < 450; i += 256) ws[i] = w1[i];
    if (t < 50) bs[t] = b1[t];
    __syncthreads();

    const int idx = blockIdx.x * 256 + t;
    if (idx >= nimg * 169) return;
    const int b   = idx / 169;
    const int pos = idx % 169;
    const int py = pos / 13, px = pos % 13;

    const float* xp = x + (size_t)b * 784 + (2 * py) * 28 + 2 * px;
    float p[4][4];
#pragma unroll
    for (int r = 0; r < 4; ++r)
#pragma unroll
        for (int c = 0; c < 4; ++c) p[r][c] = xp[r * 28 + c];

    float* hb = h1 + (size_t)b * 8480 + pos;
    if (pos < 30) h1[(size_t)b * 8480 + 8450 + pos] = 0.f;   // zero pad cols

    for (int oc = 0; oc < 50; ++oc) {
        const float* wp = &ws[oc * 9];
        const float w00 = wp[0], w01 = wp[1], w02 = wp[2];
        const float w10 = wp[3], w11 = wp[4], w12 = wp[5];
        const float w20 = wp[6], w21 = wp[7], w22 = wp[8];
        float a[2][2];
#pragma unroll
        for (int dy = 0; dy < 2; ++dy)
#pragma unroll
            for (int dx = 0; dx < 2; ++dx) {
                a[dy][dx] = p[dy + 0][dx + 0] * w00 + p[dy + 0][dx + 1] * w01 + p[dy + 0][dx + 2] * w02
                          + p[dy + 1][dx + 0] * w10 + p[dy + 1][dx + 1] * w11 + p[dy + 1][dx + 2] * w12
                          + p[dy + 2][dx + 0] * w20 + p[dy + 2][dx + 1] * w21 + p[dy + 2][dx + 2] * w22;
            }
        float v = fmaxf(fmaxf(a[0][0], a[0][1]), fmaxf(a[1][0], a[1][1])) + bs[oc];
        hb[oc * 169] = fmaxf(v, 0.f);
    }
}

// ---------------------------------------------------------------------------
// conv2 (50->50) + relu + pool. h1:[nimg,8480] -> h2:[nimg,1280] (pads zeroed)
// Block = 2 images, 256 thr = 4 waves. lane=(img,pos): img=lane/25, pos=lane%25
// (lanes 50..63 idle). Wave w covers ocs base[w]..base[w]+noc-1 (13,13,12,12),
// wave-uniform -> weights via scalar s_load (no vector-pipe cost). Patches
// from LDS copy of the 2 images (straight copy, 16 b32 reads/thread/ic).
// No __syncthreads in the ic loop. FP tree identical to r2/r4.
// ---------------------------------------------------------------------------
__global__ __launch_bounds__(256) void conv2_su(
    const float* __restrict__ h1, const float* __restrict__ w2,
    const float* __restrict__ b2, float* __restrict__ h2)
{
    __shared__ float in[2][8450];
    const int blk = blockIdx.x;
    const int t = threadIdx.x;
#pragma unroll
    for (int img = 0; img < 2; ++img)
        for (int i = t; i < 8450; i += 256)
            in[img][i] = h1[(size_t)(blk * 2 + img) * 8480 + i];
    __syncthreads();

    if (t < 60) h2[(size_t)(blk * 2 + t / 30) * 1280 + 1250 + (t % 30)] = 0.f;

    const int lane = t & 63;
    const int wv   = t >> 6;
    const int oc0  = __builtin_amdgcn_readfirstlane((wv < 2) ? wv * 13 : 26 + (wv - 2) * 12);
    const int noc  = __builtin_amdgcn_readfirstlane(13 - (wv >> 1));   // 13,13,12,12

    const bool act = (lane < 50);
    const int img2 = act ? (lane / 25) : 0;
    const int pos  = act ? (lane % 25) : 0;
    const int py = pos / 5, px = pos % 5;
    const float* ib = &in[img2][(2 * py) * 13 + 2 * px];

    float acc[13][4];
#pragma unroll
    for (int j = 0; j < 13; ++j)
#pragma unroll
        for (int q = 0; q < 4; ++q) acc[j][q] = 0.f;

#pragma unroll 1
    for (int ic = 0; ic < 50; ++ic) {
        float p[4][4];
        const float* ip = ib + ic * 169;
#pragma unroll
        for (int r = 0; r < 4; ++r)
#pragma unroll
            for (int c = 0; c < 4; ++c) p[r][c] = ip[r * 13 + c];

        const float* wic = w2 + (size_t)oc0 * 450 + ic * 9;
#pragma unroll
        for (int j = 0; j < 13; ++j) {
            if (j < noc) {
                const float* wp = wic + j * 450;
                const float w00 = wp[0], w01 = wp[1], w02 = wp[2];
                const float w10 = wp[3], w11 = wp[4], w12 = wp[5];
                const float w20 = wp[6], w21 = wp[7], w22 = wp[8];
#pragma unroll
                for (int dy = 0; dy < 2; ++dy)
#pragma unroll
                    for (int dx = 0; dx < 2; ++dx) {
                        acc[j][dy * 2 + dx] +=
                              p[dy + 0][dx + 0] * w00 + p[dy + 0][dx + 1] * w01 + p[dy + 0][dx + 2] * w02
                            + p[dy + 1][dx + 0] * w10 + p[dy + 1][dx + 1] * w11 + p[dy + 1][dx + 2] * w12
                            + p[dy + 2][dx + 0] * w20 + p[dy + 2][dx + 1] * w21 + p[dy + 2][dx + 2] * w22;
                    }
            }
        }
    }

    if (act) {
#pragma unroll
        for (int j = 0; j < 13; ++j) {
            if (j < noc) {
                float v = fmaxf(fmaxf(acc[j][0], acc[j][1]), fmaxf(acc[j][2], acc[j][3]));
                v = fmaxf(v + b2[oc0 + j], 0.f);
                h2[(size_t)(blk * 2 + img2) * 1280 + (oc0 + j) * 25 + pos] = v;
            }
        }
    }
}

// ---------------------------------------------------------------------------
// conv3 (50->50 on 5x5) + relu + pool -> f3:[nimg,50]. 4 images per block.
// ---------------------------------------------------------------------------
__global__ __launch_bounds__(256) void conv3_pool(
    const float* __restrict__ h2, const float* __restrict__ w3,
    const float* __restrict__ b3, float* __restrict__ f3)
{
    __shared__ float in[5000];
    const int blk = blockIdx.x;
    const int t = threadIdx.x;
    for (int i = t; i < 5000; i += 256) {
        const int img = i / 1250, off = i % 1250;
        in[i] = h2[(size_t)(blk * 4 + img) * 1280 + off];
    }
    __syncthreads();
    const int il = t >> 6;
    const int oc = t & 63;
    if (oc >= 50) return;

    const float* ip0 = &in[il * 1250];
    float a00 = 0.f, a01 = 0.f, a10 = 0.f, a11 = 0.f;
    for (int ic = 0; ic < 50; ++ic) {
        float p[4][4];
        const float* ip = ip0 + ic * 25;
#pragma unroll
        for (int r = 0; r < 4; ++r)
#pragma unroll
            for (int c = 0; c < 4; ++c) p[r][c] = ip[r * 5 + c];
        const float* wp = &w3[((size_t)oc * 50 + ic) * 9];
        const float w00 = wp[0], w01 = wp[1], w02 = wp[2];
        const float w10 = wp[3], w11 = wp[4], w12 = wp[5];
        const float w20 = wp[6], w21 = wp[7], w22 = wp[8];
        a00 += p[0][0]*w00 + p[0][1]*w01 + p[0][2]*w02 + p[1][0]*w10 + p[1][1]*w11 + p[1][2]*w12 + p[2][0]*w20 + p[2][1]*w21 + p[2][2]*w22;
        a01 += p[0][1]*w00 + p[0][2]*w01 + p[0][3]*w02 + p[1][1]*w10 + p[1][2]*w11 + p[1][3]*w12 + p[2][1]*w20 + p[2][2]*w21 + p[2][3]*w22;
        a10 += p[1][0]*w00 + p[1][1]*w01 + p[1][2]*w02 + p[2][0]*w10 + p[2][1]*w11 + p[2][2]*w12 + p[3][0]*w20 + p[3][1]*w21 + p[3][2]*w22;
        a11 += p[1][1]*w00 + p[1][2]*w01 + p[1][3]*w02 + p[2][1]*w10 + p[2][2]*w11 + p[2][3]*w12 + p[3][1]*w20 + p[3][2]*w21 + p[3][3]*w22;
    }
    float v = fmaxf(fmaxf(a00, a01), fmaxf(a10, a11)) + b3[oc];
    f3[(size_t)(blk * 4 + il) * 50 + oc] = fmaxf(v, 0.f);
}

// ---------------------------------------------------------------------------
// exit: z = f @ dw^T + db (2 outputs); e[b] = (z0 >= z1). fp32, block/sample.
// ---------------------------------------------------------------------------
__global__ __launch_bounds__(256) void exit_kernel(
    const float* __restrict__ F, int ldf, int K,
    const float* __restrict__ dw, const float* __restrict__ db, int* __restrict__ e)
{
    const int b = blockIdx.x;
    const int t = threadIdx.x;
    const float* f = F + (size_t)b * ldf;
    float s0 = 0.f, s1 = 0.f;
    for (int i = t; i < K; i += 256) {
        const float v = f[i];
        s0 += v * dw[i];
        s1 += v * dw[K + i];
    }
    __shared__ float r0[256];
    __shared__ float r1[256];
    r0[t] = s0; r1[t] = s1;
    __syncthreads();
    for (int s = 128; s > 0; s >>= 1) {
        if (t < s) { r0[t] += r0[t + s]; r1[t] += r1[t + s]; }
        __syncthreads();
    }
    if (t == 0) e[b] = (r0[0] + db[0] >= r1[0] + db[1]) ? 1 : 0;
}

// ---------------------------------------------------------------------------
// fp32 [N,K] -> bf16 [Np,Kp], zero-padded.
// ---------------------------------------------------------------------------
__global__ __launch_bounds__(256) void w_to_bf16(
    const float* __restrict__ src, bf16_t* __restrict__ dst, int N, int K, int Kp, int total)
{
    const int idx = blockIdx.x * 256 + threadIdx.x;
    if (idx >= total) return;
    const int n = idx / Kp, k = idx % Kp;
    const float v = (n < N && k < K) ? src[(size_t)n * K + k] : 0.f;
    dst[idx] = (bf16_t)v;
}

// ---------------------------------------------------------------------------
// MFMA GEMM: C[M,ldc] = bf16(A_f32[M,lda]) @ W_bf16[Np,Kp]^T + bias
// BM=128, BN=64, BK=32. LDS row stride 40.
// ---------------------------------------------------------------------------
__global__ __launch_bounds__(256) void gemm_f32a_bf16w(
    const float* __restrict__ A, int lda,
    const bf16_t* __restrict__ W,
    const float* __restrict__ bias, float* __restrict__ C,
    int Kp, int Nout, int ldc)
{
    __shared__ __align__(16) bf16_t As[128 * 40];
    __shared__ __align__(16) bf16_t Bs[64 * 40];

    const int t = threadIdx.x;
    const int m0 = blockIdx.x * 128;
    const int n0 = blockIdx.y * 64;
    const int wave = t >> 6;
    const int lane = t & 63;
    const int wm = (wave >> 1) * 64;
    const int wn = (wave & 1) * 32;
    const int quad = lane >> 4;
    const int lr = lane & 15;

    f32x4 acc[4][2];
#pragma unroll
    for (int i = 0; i < 4; ++i)
#pragma unroll
        for (int j = 0; j < 2; ++j) acc[i][j] = (f32x4)0.f;

    const int ar = t >> 2;          // 0..63
    const int ac = (t & 3) * 8;     // 0,8,16,24

    for (int k0 = 0; k0 < Kp; k0 += 32) {
        __syncthreads();
#pragma unroll
        for (int h = 0; h < 2; ++h) {
            const float* ap = A + (size_t)(m0 + ar + h * 64) * lda + k0 + ac;
            const float4 f0 = *(const float4*)ap;
            const float4 f1 = *(const float4*)(ap + 4);
            bf16x8 v;
            v[0] = (bf16_t)f0.x; v[1] = (bf16_t)f0.y; v[2] = (bf16_t)f0.z; v[3] = (bf16_t)f0.w;
            v[4] = (bf16_t)f1.x; v[5] = (bf16_t)f1.y; v[6] = (bf16_t)f1.z; v[7] = (bf16_t)f1.w;
            *(bf16x8*)&As[(ar + h * 64) * 40 + ac] = v;
        }
        *(uint4*)&Bs[ar * 40 + ac] = *(const uint4*)&W[(size_t)(n0 + ar) * Kp + k0 + ac];
        __syncthreads();

        bf16x8 af[4], bfr[2];
#pragma unroll
        for (int i = 0; i < 4; ++i)
            af[i] = *(const bf16x8*)&As[(wm + i * 16 + lr) * 40 + quad * 8];
#pragma unroll
        for (int j = 0; j < 2; ++j)
            bfr[j] = *(const bf16x8*)&Bs[(wn + j * 16 + lr) * 40 + quad * 8];
#pragma unroll
        for (int i = 0; i < 4; ++i)
#pragma unroll
            for (int j = 0; j < 2; ++j)
                acc[i][j] = __builtin_amdgcn_mfma_f32_16x16x32_bf16(af[i], bfr[j], acc[i][j], 0, 0, 0);
    }

#pragma unroll
    for (int j = 0; j < 2; ++j) {
        const int n = n0 + wn + j * 16 + lr;
        const float bv = (n < Nout) ? bias[n] : 0.f;
#pragma unroll
        for (int i = 0; i < 4; ++i) {
            const int mrow = m0 + wm + i * 16 + quad * 4;
#pragma unroll
            for (int r = 0; r < 4; ++r)
                C[(size_t)(mrow + r) * ldc + n] = acc[i][j][r] + bv;
        }
    }
}

// ---------------------------------------------------------------------------
// out[b,o<10] = U[b,:500] @ W[o,:500] + bias[o].
// Block: 256 thr = 16 images x 16 k-strips (lane-adjacent = k, coalesced).
// ---------------------------------------------------------------------------
__global__ __launch_bounds__(256) void lin10(
    const float* __restrict__ U, int ldu,
    const float* __restrict__ W, const float* __restrict__ bias,
    float* __restrict__ out)
{
    __shared__ float red[16][10][17];
    const int t = threadIdx.x;
    const int ks = t & 15;
    const int il = t >> 4;
    const int b  = blockIdx.x * 16 + il;
    const float* u = U + (size_t)b * ldu;

    float acc[10];
#pragma unroll
    for (int o = 0; o < 10; ++o) acc[o] = 0.f;

    for (int i = 0; i < 31; ++i) {
        const int k = ks + i * 16;          // <= 495
        const float uv = u[k];
#pragma unroll
        for (int o = 0; o < 10; ++o) acc[o] += uv * W[o * 500 + k];
    }
    {   // tail: k = 496..511, valid only k<500
        const int k = ks + 496;
        if (k < 500) {
            const float uv = u[k];
#pragma unroll
            for (int o = 0; o < 10; ++o) acc[o] += uv * W[o * 500 + k];
        }
    }
#pragma unroll
    for (int o = 0; o < 10; ++o) red[il][o][ks] = acc[o];
    __syncthreads();
    if (t < 160) {
        const int il2 = t / 10, o = t - il2 * 10;
        float s = 0.f;
#pragma unroll
        for (int q = 0; q < 16; ++q) s += red[il2][o][q];
        out[(size_t)(blockIdx.x * 16 + il2) * 10 + o] = s + bias[o];
    }
}

// ---------------------------------------------------------------------------
// u3[b,o<500] = relu(f3[b,:50] @ l1w[o,:50] + l1b[o]); u3 row stride 512.
// ---------------------------------------------------------------------------
__global__ __launch_bounds__(256) void lin500(
    const float* __restrict__ f3, const float* __restrict__ w,
    const float* __restrict__ bias, float* __restrict__ u3)
{
    __shared__ float fs[50];
    const int b = blockIdx.x;
    const int t = threadIdx.x;
    if (t < 50) fs[t] = f3[(size_t)b * 50 + t];
    __syncthreads();
    for (int o = t; o < 500; o += 256) {
        float s = 0.f;
#pragma unroll
        for (int k = 0; k < 50; ++k) s += fs[k] * w[o * 50 + k];
        u3[(size_t)b * 512 + o] = fmaxf(s + bias[o], 0.f);
    }
}

// ---------------------------------------------------------------------------
// select per exits, log_softmax over 10, write final output (full batch).
// ---------------------------------------------------------------------------
__global__ __launch_bounds__(256) void final_select(
    const int* __restrict__ e1, const int* __restrict__ e2,
    const float* __restrict__ o1, const float* __restrict__ o2,
    const float* __restrict__ o3, float* __restrict__ out)
{
    const int b = blockIdx.x * 256 + threadIdx.x;
    if (b >= B_IMG) return;
    const float* src = e1[b] ? o1 : (e2[b] ? o2 : o3);
    src += (size_t)b * 10;
    float v[10];
    float m = -3.4e38f;
#pragma unroll
    for (int o = 0; o < 10; ++o) { v[o] = src[o]; m = fmaxf(m, v[o]); }
    float s = 0.f;
#pragma unroll
    for (int o = 0; o < 10; ++o) s += expf(v[o] - m);
    const float ls = logf(s);
#pragma unroll
    for (int o = 0; o < 10; ++o) out[(size_t)b * 10 + o] = v[o] - m - ls;
}

// ---------------------------------------------------------------------------
static inline size_t align256(size_t v) { return (v + 255) & ~(size_t)255; }

extern "C" void kernel_launch(void* const* d_in, const int* in_sizes, int n_in,
                              void* d_out, int out_size, void* d_ws, size_t ws_size,
                              hipStream_t stream)
{
    const float* x     = (const float*)d_in[0];
    const float* c1w   = (const float*)d_in[1];
    const float* c1b   = (const float*)d_in[2];
    const float* c2w   = (const float*)d_in[3];
    const float* c2b   = (const float*)d_in[4];
    const float* c3w   = (const float*)d_in[5];
    const float* c3b   = (const float*)d_in[6];
    const float* l1c1w = (const float*)d_in[7];
    const float* l1c1b = (const float*)d_in[8];
    const float* l2c1w = (const float*)d_in[9];
    const float* l2c1b = (const float*)d_in[10];
    const float* l1c2w = (const float*)d_in[11];
    const float* l1c2b = (const float*)d_in[12];
    const float* l2c2w = (const float*)d_in[13];
    const float* l2c2b = (const float*)d_in[14];
    const float* l1w   = (const float*)d_in[15];
    const float* l1b   = (const float*)d_in[16];
    const float* l2w   = (const float*)d_in[17];
    const float* l2b   = (const float*)d_in[18];
    const float* d1w   = (const float*)d_in[19];
    const float* d1b   = (const float*)d_in[20];
    const float* d2w   = (const float*)d_in[21];
    const float* d2b   = (const float*)d_in[22];

    // ---- persistent layout (full batch) ----
    size_t off = 0;
    const size_t oWb1  = off; off = align256(off + (size_t)512 * 8480 * 2);
    const size_t oWb2  = off; off = align256(off + (size_t)512 * 1280 * 2);
    const size_t oOut1 = off; off = align256(off + (size_t)B_IMG * 10 * 4);
    const size_t oOut2 = off; off = align256(off + (size_t)B_IMG * 10 * 4);
    const size_t oOut3 = off; off = align256(off + (size_t)B_IMG * 10 * 4);
    const size_t oE1   = off; off = align256(off + (size_t)B_IMG * 4);
    const size_t oE2   = off; off = align256(off + (size_t)B_IMG * 4);
    const size_t persist = off;

    // ---- per-chunk bytes: h1 + h2 + u(shared) + f3 ----
    auto chunk_bytes = [](int C) {
        size_t s = 0;
        s += align256((size_t)C * 8480 * 4);   // h1
        s += align256((size_t)C * 1280 * 4);   // h2
        s += align256((size_t)C * 512 * 4);    // u (shared across stages)
        s += align256((size_t)C * 50 * 4);     // f3
        return s;
    };
    int C = B_IMG;
    while (C > 256 && persist + chunk_bytes(C) > ws_size) C >>= 1;

    char* ws = (char*)d_ws;
    bf16_t* Wb1  = (bf16_t*)(ws + oWb1);
    bf16_t* Wb2  = (bf16_t*)(ws + oWb2);
    float*  out1 = (float*) (ws + oOut1);
    float*  out2 = (float*) (ws + oOut2);
    float*  out3 = (float*) (ws + oOut3);
    int*    e1   = (int*)   (ws + oE1);
    int*    e2   = (int*)   (ws + oE2);

    size_t co = persist;
    float* h1 = (float*)(ws + co); co += align256((size_t)C * 8480 * 4);
    float* h2 = (float*)(ws + co); co += align256((size_t)C * 1280 * 4);
    float* u  = (float*)(ws + co); co += align256((size_t)C * 512 * 4);
    float* f3 = (float*)(ws + co); co += align256((size_t)C * 50 * 4);

    float* out = (float*)d_out;

    // weight conversion (once)
    w_to_bf16<<<(512 * 8480) / 256, 256, 0, stream>>>(l1c1w, Wb1, 500, 8450, 8480, 512 * 8480);
    w_to_bf16<<<(512 * 1280) / 256, 256, 0, stream>>>(l1c2w, Wb2, 500, 1250, 1280, 512 * 1280);

    for (int b0 = 0; b0 < B_IMG; b0 += C) {
        // stage 1
        conv1_pool<<<(C * 169 + 255) / 256, 256, 0, stream>>>(x + (size_t)b0 * 784, c1w, c1b, h1, C);
        exit_kernel<<<C, 256, 0, stream>>>(h1, 8480, 8450, d1w, d1b, e1 + b0);
        gemm_f32a_bf16w<<<dim3(C / 128, 8), 256, 0, stream>>>(h1, 8480, Wb1, l1c1b, u, 8480, 500, 512);
        lin10<<<C / 16, 256, 0, stream>>>(u, 512, l2c1w, l2c1b, out1 + (size_t)b0 * 10);

        // stage 2
        conv2_su<<<C / 2, 256, 0, stream>>>(h1, c2w, c2b, h2);
        exit_kernel<<<C, 256, 0, stream>>>(h2, 1280, 1250, d2w, d2b, e2 + b0);
        gemm_f32a_bf16w<<<dim3(C / 128, 8), 256, 0, stream>>>(h2, 1280, Wb2, l1c2b, u, 1280, 500, 512);
        lin10<<<C / 16, 256, 0, stream>>>(u, 512, l2c2w, l2c2b, out2 + (size_t)b0 * 10);

        // stage 3
        conv3_pool<<<C / 4, 256, 0, stream>>>(h2, c3w, c3b, f3);
        lin500<<<C, 256, 0, stream>>>(f3, l1w, l1b, u);
        lin10<<<C / 16, 256, 0, stream>>>(u, 512, l2w, l2b, out3 + (size_t)b0 * 10);
    }

    final_select<<<B_IMG / 256, 256, 0, stream>>>(e1, e2, out1, out2, out3, out);

    (void)in_sizes; (void)n_in; (void)out_size; (void)ws_size;
}

// Round 8
// 993.747 us; speedup vs baseline: 1.6959x; 1.2827x over previous
//
#include <hip/hip_runtime.h>
#include <hip/hip_bf16.h>
#include <cstdint>

// ---------------------------------------------------------------------------
// ThreeLayerCNN (BranchyNet early-exit), B=4096.
// Precision: conv1/conv2/exit1/exit2 fp32 (argmax parity with numpy ref);
// big FC GEMMs (l1c1, l1c2) bf16 MFMA w/ fp32 accum (output tol 0.146).
// Round 8 (consolidation on the r4=934us structure):
//  - conv2: r4 thread map, but weights pre-transposed to w2p[ic][oc][12] ->
//    ds_read_b128 weight reads (45 b32 -> 15 b128/thread/ic) + float4 wbuf
//    staging. Same values, same FMA tree -> h2 identical (exit2 parity).
//  - gemm: 128x128 tile (m93 shape) -> half the A-panel re-reads, 2x MFMA
//    per staging byte.
// ---------------------------------------------------------------------------

typedef __bf16 bf16_t;
typedef __bf16 bf16x8 __attribute__((ext_vector_type(8)));
typedef float  f32x4  __attribute__((ext_vector_type(4)));

#define B_IMG 4096

// ---------------------------------------------------------------------------
// conv1 (1->50, 3x3) + relu + maxpool2.  x:[nimg,1,28,28] -> h1:[nimg,8480]
// ---------------------------------------------------------------------------
__global__ __launch_bounds__(256) void conv1_pool(
    const float* __restrict__ x, const float* __restrict__ w1,
    const float* __restrict__ b1, float* __restrict__ h1, int nimg)
{
    __shared__ float ws[450];
    __shared__ float bs[50];
    const int t = threadIdx.x;
    for (int i = t; i < 450; i += 256) ws[i] = w1[i];
    if (t < 50) bs[t] = b1[t];
    __syncthreads();

    const int idx = blockIdx.x * 256 + t;
    if (idx >= nimg * 169) return;
    const int b   = idx / 169;
    const int pos = idx % 169;
    const int py = pos / 13, px = pos % 13;

    const float* xp = x + (size_t)b * 784 + (2 * py) * 28 + 2 * px;
    float p[4][4];
#pragma unroll
    for (int r = 0; r < 4; ++r)
#pragma unroll
        for (int c = 0; c < 4; ++c) p[r][c] = xp[r * 28 + c];

    float* hb = h1 + (size_t)b * 8480 + pos;
    if (pos < 30) h1[(size_t)b * 8480 + 8450 + pos] = 0.f;   // zero pad cols

    for (int oc = 0; oc < 50; ++oc) {
        const float* wp = &ws[oc * 9];
        const float w00 = wp[0], w01 = wp[1], w02 = wp[2];
        const float w10 = wp[3], w11 = wp[4], w12 = wp[5];
        const float w20 = wp[6], w21 = wp[7], w22 = wp[8];
        float a[2][2];
#pragma unroll
        for (int dy = 0; dy < 2; ++dy)
#pragma unroll
            for (int dx = 0; dx < 2; ++dx) {
                a[dy][dx] = p[dy + 0][dx + 0] * w00 + p[dy + 0][dx + 1] * w01 + p[dy + 0][dx + 2] * w02
                          + p[dy + 1][dx + 0] * w10 + p[dy + 1][dx + 1] * w11 + p[dy + 1][dx + 2] * w12
                          + p[dy + 2][dx + 0] * w20 + p[dy + 2][dx + 1] * w21 + p[dy + 2][dx + 2] * w22;
            }
        float v = fmaxf(fmaxf(a[0][0], a[0][1]), fmaxf(a[1][0], a[1][1])) + bs[oc];
        hb[oc * 169] = fmaxf(v, 0.f);
    }
}

// ---------------------------------------------------------------------------
// w2 [oc][ic][9] -> w2p [ic][oc][12] (pad 9->12 with zeros), 50x600 floats.
// ---------------------------------------------------------------------------
__global__ __launch_bounds__(256) void w2_transpose(
    const float* __restrict__ w2, float* __restrict__ w2p)
{
    const int idx = blockIdx.x * 256 + threadIdx.x;
    if (idx >= 50 * 600) return;
    const int ic = idx / 600, r = idx % 600, oc = r / 12, j = r % 12;
    w2p[idx] = (j < 9) ? w2[oc * 450 + ic * 9 + j] : 0.f;
}

// ---------------------------------------------------------------------------
// conv2 (50->50) + relu + pool. h1:[nimg,8480] -> h2:[nimg,1280] (pads zeroed)
// r4 structure: block per image, thread = 5 oc x 1 pooled pos.
// Weights from w2p via ds_read_b128 (3 per oc); wbuf staged as float4 copies,
// double-buffered in 4-ic chunks. Same weight values into the same FMA
// expression tree as r4 -> h2 identical (exit2 argmax parity).
// ---------------------------------------------------------------------------
__global__ __launch_bounds__(256) void conv2_pool(
    const float* __restrict__ h1, const float* __restrict__ w2p,
    const float* __restrict__ b2, float* __restrict__ h2)
{
    __shared__ float in[8450];
    __shared__ __align__(16) float wbuf[2][2400];   // [buf][icl*600 + oc*12 + j]
    const int b = blockIdx.x;
    const int t = threadIdx.x;
    for (int i = t; i < 8450; i += 256) in[i] = h1[(size_t)b * 8480 + i];
    {   // stage ic 0..3 (2400 floats = 600 float4)
        const float4* src = (const float4*)w2p;
        float4* dst = (float4*)wbuf[0];
        for (int s = t; s < 600; s += 256) dst[s] = src[s];
    }
    __syncthreads();
    if (t < 30) h2[(size_t)b * 1280 + 1250 + t] = 0.f;       // zero pad cols

    const int ocg = t / 25;
    const int pos = t % 25;
    const int py = pos / 5, px = pos % 5;
    const int oc0 = ocg * 5;
    const bool act = (t < 250);

    float acc[5][4];
#pragma unroll
    for (int j = 0; j < 5; ++j)
#pragma unroll
        for (int q = 0; q < 4; ++q) acc[j][q] = 0.f;

    const float* ib = &in[(2 * py) * 13 + 2 * px];

    for (int ic0 = 0; ic0 < 50; ic0 += 4) {
        const int cur = (ic0 >> 2) & 1;
        if (ic0 + 4 < 50) {           // prefetch next <=4-ic weight chunk
            const int nxt = cur ^ 1;
            const int nic2 = (50 - ic0 - 4 < 4) ? (50 - ic0 - 4) : 4;
            const float4* src = (const float4*)(w2p + (size_t)(ic0 + 4) * 600);
            float4* dst = (float4*)wbuf[nxt];
            for (int s = t; s < nic2 * 150; s += 256) dst[s] = src[s];
        }
        if (act) {
            const int nic = (50 - ic0 < 4) ? (50 - ic0) : 4;
            for (int icl = 0; icl < nic; ++icl) {
                const int ic = ic0 + icl;
                float p[4][4];
                const float* ip = ib + ic * 169;
#pragma unroll
                for (int r = 0; r < 4; ++r)
#pragma unroll
                    for (int c = 0; c < 4; ++c) p[r][c] = ip[r * 13 + c];
                const float* wl = &wbuf[cur][icl * 600 + oc0 * 12];
#pragma unroll
                for (int j = 0; j < 5; ++j) {
                    const f32x4 wv0 = *(const f32x4*)(wl + j * 12);
                    const f32x4 wv1 = *(const f32x4*)(wl + j * 12 + 4);
                    const f32x4 wv2 = *(const f32x4*)(wl + j * 12 + 8);
                    const float w00 = wv0[0], w01 = wv0[1], w02 = wv0[2];
                    const float w10 = wv0[3], w11 = wv1[0], w12 = wv1[1];
                    const float w20 = wv1[2], w21 = wv1[3], w22 = wv2[0];
#pragma unroll
                    for (int dy = 0; dy < 2; ++dy)
#pragma unroll
                        for (int dx = 0; dx < 2; ++dx) {
                            acc[j][dy * 2 + dx] +=
                                  p[dy + 0][dx + 0] * w00 + p[dy + 0][dx + 1] * w01 + p[dy + 0][dx + 2] * w02
                                + p[dy + 1][dx + 0] * w10 + p[dy + 1][dx + 1] * w11 + p[dy + 1][dx + 2] * w12
                                + p[dy + 2][dx + 0] * w20 + p[dy + 2][dx + 1] * w21 + p[dy + 2][dx + 2] * w22;
                        }
                }
            }
        }
        __syncthreads();
    }

    if (act) {
#pragma unroll
        for (int j = 0; j < 5; ++j) {
            float v = fmaxf(fmaxf(acc[j][0], acc[j][1]), fmaxf(acc[j][2], acc[j][3]));
            h2[(size_t)b * 1280 + (oc0 + j) * 25 + pos] = fmaxf(v + b2[oc0 + j], 0.f);
        }
    }
}

// ---------------------------------------------------------------------------
// conv3 (50->50 on 5x5) + relu + pool -> f3:[nimg,50]. 4 images per block.
// ---------------------------------------------------------------------------
__global__ __launch_bounds__(256) void conv3_pool(
    const float* __restrict__ h2, const float* __restrict__ w3,
    const float* __restrict__ b3, float* __restrict__ f3)
{
    __shared__ float in[5000];
    const int blk = blockIdx.x;
    const int t = threadIdx.x;
    for (int i = t; i < 5000; i += 256) {
        const int img = i / 1250, off = i % 1250;
        in[i] = h2[(size_t)(blk * 4 + img) * 1280 + off];
    }
    __syncthreads();
    const int il = t >> 6;
    const int oc = t & 63;
    if (oc >= 50) return;

    const float* ip0 = &in[il * 1250];
    float a00 = 0.f, a01 = 0.f, a10 = 0.f, a11 = 0.f;
    for (int ic = 0; ic < 50; ++ic) {
        float p[4][4];
        const float* ip = ip0 + ic * 25;
#pragma unroll
        for (int r = 0; r < 4; ++r)
#pragma unroll
            for (int c = 0; c < 4; ++c) p[r][c] = ip[r * 5 + c];
        const float* wp = &w3[((size_t)oc * 50 + ic) * 9];
        const float w00 = wp[0], w01 = wp[1], w02 = wp[2];
        const float w10 = wp[3], w11 = wp[4], w12 = wp[5];
        const float w20 = wp[6], w21 = wp[7], w22 = wp[8];
        a00 += p[0][0]*w00 + p[0][1]*w01 + p[0][2]*w02 + p[1][0]*w10 + p[1][1]*w11 + p[1][2]*w12 + p[2][0]*w20 + p[2][1]*w21 + p[2][2]*w22;
        a01 += p[0][1]*w00 + p[0][2]*w01 + p[0][3]*w02 + p[1][1]*w10 + p[1][2]*w11 + p[1][3]*w12 + p[2][1]*w20 + p[2][2]*w21 + p[2][3]*w22;
        a10 += p[1][0]*w00 + p[1][1]*w01 + p[1][2]*w02 + p[2][0]*w10 + p[2][1]*w11 + p[2][2]*w12 + p[3][0]*w20 + p[3][1]*w21 + p[3][2]*w22;
        a11 += p[1][1]*w00 + p[1][2]*w01 + p[1][3]*w02 + p[2][1]*w10 + p[2][2]*w11 + p[2][3]*w12 + p[3][1]*w20 + p[3][2]*w21 + p[3][3]*w22;
    }
    float v = fmaxf(fmaxf(a00, a01), fmaxf(a10, a11)) + b3[oc];
    f3[(size_t)(blk * 4 + il) * 50 + oc] = fmaxf(v, 0.f);
}

// ---------------------------------------------------------------------------
// exit: z = f @ dw^T + db (2 outputs); e[b] = (z0 >= z1). fp32, block/sample.
// ---------------------------------------------------------------------------
__global__ __launch_bounds__(256) void exit_kernel(
    const float* __restrict__ F, int ldf, int K,
    const float* __restrict__ dw, const float* __restrict__ db, int* __restrict__ e)
{
    const int b = blockIdx.x;
    const int t = threadIdx.x;
    const float* f = F + (size_t)b * ldf;
    float s0 = 0.f, s1 = 0.f;
    for (int i = t; i < K; i += 256) {
        const float v = f[i];
        s0 += v * dw[i];
        s1 += v * dw[K + i];
    }
    __shared__ float r0[256];
    __shared__ float r1[256];
    r0[t] = s0; r1[t] = s1;
    __syncthreads();
    for (int s = 128; s > 0; s >>= 1) {
        if (t < s) { r0[t] += r0[t + s]; r1[t] += r1[t + s]; }
        __syncthreads();
    }
    if (t == 0) e[b] = (r0[0] + db[0] >= r1[0] + db[1]) ? 1 : 0;
}

// ---------------------------------------------------------------------------
// fp32 [N,K] -> bf16 [Np,Kp], zero-padded.
// ---------------------------------------------------------------------------
__global__ __launch_bounds__(256) void w_to_bf16(
    const float* __restrict__ src, bf16_t* __restrict__ dst, int N, int K, int Kp, int total)
{
    const int idx = blockIdx.x * 256 + threadIdx.x;
    if (idx >= total) return;
    const int n = idx / Kp, k = idx % Kp;
    const float v = (n < N && k < K) ? src[(size_t)n * K + k] : 0.f;
    dst[idx] = (bf16_t)v;
}

// ---------------------------------------------------------------------------
// MFMA GEMM: C[M,ldc] = bf16(A_f32[M,lda]) @ W_bf16[Np,Kp]^T + bias
// BM=128, BN=128, BK=32 (m93 shape). 4 waves 2x2, wave tile 64x64 (4x4 acc).
// LDS row stride 40.
// ---------------------------------------------------------------------------
__global__ __launch_bounds__(256) void gemm_f32a_bf16w(
    const float* __restrict__ A, int lda,
    const bf16_t* __restrict__ W,
    const float* __restrict__ bias, float* __restrict__ C,
    int Kp, int Nout, int ldc)
{
    __shared__ __align__(16) bf16_t As[128 * 40];
    __shared__ __align__(16) bf16_t Bs[128 * 40];

    const int t = threadIdx.x;
    const int m0 = blockIdx.x * 128;
    const int n0 = blockIdx.y * 128;
    const int wave = t >> 6;
    const int lane = t & 63;
    const int wm = (wave >> 1) * 64;
    const int wn = (wave & 1) * 64;
    const int quad = lane >> 4;
    const int lr = lane & 15;

    f32x4 acc[4][4];
#pragma unroll
    for (int i = 0; i < 4; ++i)
#pragma unroll
        for (int j = 0; j < 4; ++j) acc[i][j] = (f32x4)0.f;

    const int ar = t >> 2;          // 0..63
    const int ac = (t & 3) * 8;     // 0,8,16,24
    const int br = t >> 1;          // 0..127
    const int bc = (t & 1) * 16;    // 0,16

    for (int k0 = 0; k0 < Kp; k0 += 32) {
        __syncthreads();
#pragma unroll
        for (int h = 0; h < 2; ++h) {
            const float* ap = A + (size_t)(m0 + ar + h * 64) * lda + k0 + ac;
            const float4 f0 = *(const float4*)ap;
            const float4 f1 = *(const float4*)(ap + 4);
            bf16x8 v;
            v[0] = (bf16_t)f0.x; v[1] = (bf16_t)f0.y; v[2] = (bf16_t)f0.z; v[3] = (bf16_t)f0.w;
            v[4] = (bf16_t)f1.x; v[5] = (bf16_t)f1.y; v[6] = (bf16_t)f1.z; v[7] = (bf16_t)f1.w;
            *(bf16x8*)&As[(ar + h * 64) * 40 + ac] = v;
        }
        const bf16_t* wp = &W[(size_t)(n0 + br) * Kp + k0 + bc];
        *(uint4*)&Bs[br * 40 + bc]     = *(const uint4*)wp;
        *(uint4*)&Bs[br * 40 + bc + 8] = *(const uint4*)(wp + 8);
        __syncthreads();

        bf16x8 af[4], bfr[4];
#pragma unroll
        for (int i = 0; i < 4; ++i)
            af[i] = *(const bf16x8*)&As[(wm + i * 16 + lr) * 40 + quad * 8];
#pragma unroll
        for (int j = 0; j < 4; ++j)
            bfr[j] = *(const bf16x8*)&Bs[(wn + j * 16 + lr) * 40 + quad * 8];
#pragma unroll
        for (int i = 0; i < 4; ++i)
#pragma unroll
            for (int j = 0; j < 4; ++j)
                acc[i][j] = __builtin_amdgcn_mfma_f32_16x16x32_bf16(af[i], bfr[j], acc[i][j], 0, 0, 0);
    }

#pragma unroll
    for (int j = 0; j < 4; ++j) {
        const int n = n0 + wn + j * 16 + lr;
        const float bv = (n < Nout) ? bias[n] : 0.f;
#pragma unroll
        for (int i = 0; i < 4; ++i) {
            const int mrow = m0 + wm + i * 16 + quad * 4;
#pragma unroll
            for (int r = 0; r < 4; ++r)
                C[(size_t)(mrow + r) * ldc + n] = acc[i][j][r] + bv;
        }
    }
}

// ---------------------------------------------------------------------------
// out[b,o<10] = U[b,:500] @ W[o,:500] + bias[o].
// Block: 256 thr = 16 images x 16 k-strips (lane-adjacent = k, coalesced).
// ---------------------------------------------------------------------------
__global__ __launch_bounds__(256) void lin10(
    const float* __restrict__ U, int ldu,
    const float* __restrict__ W, const float* __restrict__ bias,
    float* __restrict__ out)
{
    __shared__ float red[16][10][17];
    const int t = threadIdx.x;
    const int ks = t & 15;
    const int il = t >> 4;
    const int b  = blockIdx.x * 16 + il;
    const float* u = U + (size_t)b * ldu;

    float acc[10];
#pragma unroll
    for (int o = 0; o < 10; ++o) acc[o] = 0.f;

    for (int i = 0; i < 31; ++i) {
        const int k = ks + i * 16;          // <= 495
        const float uv = u[k];
#pragma unroll
        for (int o = 0; o < 10; ++o) acc[o] += uv * W[o * 500 + k];
    }
    {   // tail: k = 496..511, valid only k<500
        const int k = ks + 496;
        if (k < 500) {
            const float uv = u[k];
#pragma unroll
            for (int o = 0; o < 10; ++o) acc[o] += uv * W[o * 500 + k];
        }
    }
#pragma unroll
    for (int o = 0; o < 10; ++o) red[il][o][ks] = acc[o];
    __syncthreads();
    if (t < 160) {
        const int il2 = t / 10, o = t - il2 * 10;
        float s = 0.f;
#pragma unroll
        for (int q = 0; q < 16; ++q) s += red[il2][o][q];
        out[(size_t)(blockIdx.x * 16 + il2) * 10 + o] = s + bias[o];
    }
}

// ---------------------------------------------------------------------------
// u3[b,o<500] = relu(f3[b,:50] @ l1w[o,:50] + l1b[o]); u3 row stride 512.
// ---------------------------------------------------------------------------
__global__ __launch_bounds__(256) void lin500(
    const float* __restrict__ f3, const float* __restrict__ w,
    const float* __restrict__ bias, float* __restrict__ u3)
{
    __shared__ float fs[50];
    const int b = blockIdx.x;
    const int t = threadIdx.x;
    if (t < 50) fs[t] = f3[(size_t)b * 50 + t];
    __syncthreads();
    for (int o = t; o < 500; o += 256) {
        float s = 0.f;
#pragma unroll
        for (int k = 0; k < 50; ++k) s += fs[k] * w[o * 50 + k];
        u3[(size_t)b * 512 + o] = fmaxf(s + bias[o], 0.f);
    }
}

// ---------------------------------------------------------------------------
// select per exits, log_softmax over 10, write final output (full batch).
// ---------------------------------------------------------------------------
__global__ __launch_bounds__(256) void final_select(
    const int* __restrict__ e1, const int* __restrict__ e2,
    const float* __restrict__ o1, const float* __restrict__ o2,
    const float* __restrict__ o3, float* __restrict__ out)
{
    const int b = blockIdx.x * 256 + threadIdx.x;
    if (b >= B_IMG) return;
    const float* src = e1[b] ? o1 : (e2[b] ? o2 : o3);
    src += (size_t)b * 10;
    float v[10];
    float m = -3.4e38f;
#pragma unroll
    for (int o = 0; o < 10; ++o) { v[o] = src[o]; m = fmaxf(m, v[o]); }
    float s = 0.f;
#pragma unroll
    for (int o = 0; o < 10; ++o) s += expf(v[o] - m);
    const float ls = logf(s);
#pragma unroll
    for (int o = 0; o < 10; ++o) out[(size_t)b * 10 + o] = v[o] - m - ls;
}

// ---------------------------------------------------------------------------
static inline size_t align256(size_t v) { return (v + 255) & ~(size_t)255; }

extern "C" void kernel_launch(void* const* d_in, const int* in_sizes, int n_in,
                              void* d_out, int out_size, void* d_ws, size_t ws_size,
                              hipStream_t stream)
{
    const float* x     = (const float*)d_in[0];
    const float* c1w   = (const float*)d_in[1];
    const float* c1b   = (const float*)d_in[2];
    const float* c2w   = (const float*)d_in[3];
    const float* c2b   = (const float*)d_in[4];
    const float* c3w   = (const float*)d_in[5];
    const float* c3b   = (const float*)d_in[6];
    const float* l1c1w = (const float*)d_in[7];
    const float* l1c1b = (const float*)d_in[8];
    const float* l2c1w = (const float*)d_in[9];
    const float* l2c1b = (const float*)d_in[10];
    const float* l1c2w = (const float*)d_in[11];
    const float* l1c2b = (const float*)d_in[12];
    const float* l2c2w = (const float*)d_in[13];
    const float* l2c2b = (const float*)d_in[14];
    const float* l1w   = (const float*)d_in[15];
    const float* l1b   = (const float*)d_in[16];
    const float* l2w   = (const float*)d_in[17];
    const float* l2b   = (const float*)d_in[18];
    const float* d1w   = (const float*)d_in[19];
    const float* d1b   = (const float*)d_in[20];
    const float* d2w   = (const float*)d_in[21];
    const float* d2b   = (const float*)d_in[22];

    // ---- persistent layout (full batch) ----
    size_t off = 0;
    const size_t oWb1  = off; off = align256(off + (size_t)512 * 8480 * 2);
    const size_t oWb2  = off; off = align256(off + (size_t)512 * 1280 * 2);
    const size_t oW2P  = off; off = align256(off + (size_t)50 * 600 * 4);
    const size_t oOut1 = off; off = align256(off + (size_t)B_IMG * 10 * 4);
    const size_t oOut2 = off; off = align256(off + (size_t)B_IMG * 10 * 4);
    const size_t oOut3 = off; off = align256(off + (size_t)B_IMG * 10 * 4);
    const size_t oE1   = off; off = align256(off + (size_t)B_IMG * 4);
    const size_t oE2   = off; off = align256(off + (size_t)B_IMG * 4);
    const size_t persist = off;

    // ---- per-chunk bytes: h1 + h2 + u(shared) + f3 ----
    auto chunk_bytes = [](int C) {
        size_t s = 0;
        s += align256((size_t)C * 8480 * 4);   // h1
        s += align256((size_t)C * 1280 * 4);   // h2
        s += align256((size_t)C * 512 * 4);    // u (shared across stages)
        s += align256((size_t)C * 50 * 4);     // f3
        return s;
    };
    int C = B_IMG;
    while (C > 256 && persist + chunk_bytes(C) > ws_size) C >>= 1;

    char* ws = (char*)d_ws;
    bf16_t* Wb1  = (bf16_t*)(ws + oWb1);
    bf16_t* Wb2  = (bf16_t*)(ws + oWb2);
    float*  w2p  = (float*) (ws + oW2P);
    float*  out1 = (float*) (ws + oOut1);
    float*  out2 = (float*) (ws + oOut2);
    float*  out3 = (float*) (ws + oOut3);
    int*    e1   = (int*)   (ws + oE1);
    int*    e2   = (int*)   (ws + oE2);

    size_t co = persist;
    float* h1 = (float*)(ws + co); co += align256((size_t)C * 8480 * 4);
    float* h2 = (float*)(ws + co); co += align256((size_t)C * 1280 * 4);
    float* u  = (float*)(ws + co); co += align256((size_t)C * 512 * 4);
    float* f3 = (float*)(ws + co); co += align256((size_t)C * 50 * 4);

    float* out = (float*)d_out;

    // weight conversion (once)
    w_to_bf16<<<(512 * 8480) / 256, 256, 0, stream>>>(l1c1w, Wb1, 500, 8450, 8480, 512 * 8480);
    w_to_bf16<<<(512 * 1280) / 256, 256, 0, stream>>>(l1c2w, Wb2, 500, 1250, 1280, 512 * 1280);
    w2_transpose<<<(50 * 600 + 255) / 256, 256, 0, stream>>>(c2w, w2p);

    for (int b0 = 0; b0 < B_IMG; b0 += C) {
        // stage 1
        conv1_pool<<<(C * 169 + 255) / 256, 256, 0, stream>>>(x + (size_t)b0 * 784, c1w, c1b, h1, C);
        exit_kernel<<<C, 256, 0, stream>>>(h1, 8480, 8450, d1w, d1b, e1 + b0);
        gemm_f32a_bf16w<<<dim3(C / 128, 4), 256, 0, stream>>>(h1, 8480, Wb1, l1c1b, u, 8480, 500, 512);
        lin10<<<C / 16, 256, 0, stream>>>(u, 512, l2c1w, l2c1b, out1 + (size_t)b0 * 10);

        // stage 2
        conv2_pool<<<C, 256, 0, stream>>>(h1, w2p, c2b, h2);
        exit_kernel<<<C, 256, 0, stream>>>(h2, 1280, 1250, d2w, d2b, e2 + b0);
        gemm_f32a_bf16w<<<dim3(C / 128, 4), 256, 0, stream>>>(h2, 1280, Wb2, l1c2b, u, 1280, 500, 512);
        lin10<<<C / 16, 256, 0, stream>>>(u, 512, l2c2w, l2c2b, out2 + (size_t)b0 * 10);

        // stage 3
        conv3_pool<<<C / 4, 256, 0, stream>>>(h2, c3w, c3b, f3);
        lin500<<<C, 256, 0, stream>>>(f3, l1w, l1b, u);
        lin10<<<C / 16, 256, 0, stream>>>(u, 512, l2w, l2b, out3 + (size_t)b0 * 10);
    }

    final_select<<<B_IMG / 256, 256, 0, stream>>>(e1, e2, out1, out2, out3, out);

    (void)in_sizes; (void)n_in; (void)out_size; (void)ws_size;
}

// Round 9
// 776.027 us; speedup vs baseline: 2.1717x; 1.2806x over previous
//
#include <hip/hip_runtime.h>
#include <hip/hip_bf16.h>
#include <cstdint>

// ---------------------------------------------------------------------------
// ThreeLayerCNN (BranchyNet early-exit), B=4096.
// Precision: conv1/conv2/exit1/exit2 fp32 (argmax parity with numpy ref);
// big FC GEMMs (l1c1, l1c2) bf16 MFMA w/ fp32 accum (output tol 0.146).
// Round 9:
//  - gemm back to BM=128/BN=64 (r4-proven) + split-K=2 via grid z ->
//    512 blocks (2/CU, 8 waves/CU) instead of 256 (1/CU). Deterministic:
//    z=0 writes u (with bias), z=1 writes upart (no bias); lin10_2 sums.
//  - conv2_pool = r8 version (318 us, b128 weight reads).
// ---------------------------------------------------------------------------

typedef __bf16 bf16_t;
typedef __bf16 bf16x8 __attribute__((ext_vector_type(8)));
typedef float  f32x4  __attribute__((ext_vector_type(4)));

#define B_IMG 4096

// ---------------------------------------------------------------------------
// conv1 (1->50, 3x3) + relu + maxpool2.  x:[nimg,1,28,28] -> h1:[nimg,8480]
// ---------------------------------------------------------------------------
__global__ __launch_bounds__(256) void conv1_pool(
    const float* __restrict__ x, const float* __restrict__ w1,
    const float* __restrict__ b1, float* __restrict__ h1, int nimg)
{
    __shared__ float ws[450];
    __shared__ float bs[50];
    const int t = threadIdx.x;
    for (int i = t; i < 450; i += 256) ws[i] = w1[i];
    if (t < 50) bs[t] = b1[t];
    __syncthreads();

    const int idx = blockIdx.x * 256 + t;
    if (idx >= nimg * 169) return;
    const int b   = idx / 169;
    const int pos = idx % 169;
    const int py = pos / 13, px = pos % 13;

    const float* xp = x + (size_t)b * 784 + (2 * py) * 28 + 2 * px;
    float p[4][4];
#pragma unroll
    for (int r = 0; r < 4; ++r)
#pragma unroll
        for (int c = 0; c < 4; ++c) p[r][c] = xp[r * 28 + c];

    float* hb = h1 + (size_t)b * 8480 + pos;
    if (pos < 30) h1[(size_t)b * 8480 + 8450 + pos] = 0.f;   // zero pad cols

    for (int oc = 0; oc < 50; ++oc) {
        const float* wp = &ws[oc * 9];
        const float w00 = wp[0], w01 = wp[1], w02 = wp[2];
        const float w10 = wp[3], w11 = wp[4], w12 = wp[5];
        const float w20 = wp[6], w21 = wp[7], w22 = wp[8];
        float a[2][2];
#pragma unroll
        for (int dy = 0; dy < 2; ++dy)
#pragma unroll
            for (int dx = 0; dx < 2; ++dx) {
                a[dy][dx] = p[dy + 0][dx + 0] * w00 + p[dy + 0][dx + 1] * w01 + p[dy + 0][dx + 2] * w02
                          + p[dy + 1][dx + 0] * w10 + p[dy + 1][dx + 1] * w11 + p[dy + 1][dx + 2] * w12
                          + p[dy + 2][dx + 0] * w20 + p[dy + 2][dx + 1] * w21 + p[dy + 2][dx + 2] * w22;
            }
        float v = fmaxf(fmaxf(a[0][0], a[0][1]), fmaxf(a[1][0], a[1][1])) + bs[oc];
        hb[oc * 169] = fmaxf(v, 0.f);
    }
}

// ---------------------------------------------------------------------------
// w2 [oc][ic][9] -> w2p [ic][oc][12] (pad 9->12 with zeros), 50x600 floats.
// ---------------------------------------------------------------------------
__global__ __launch_bounds__(256) void w2_transpose(
    const float* __restrict__ w2, float* __restrict__ w2p)
{
    const int idx = blockIdx.x * 256 + threadIdx.x;
    if (idx >= 50 * 600) return;
    const int ic = idx / 600, r = idx % 600, oc = r / 12, j = r % 12;
    w2p[idx] = (j < 9) ? w2[oc * 450 + ic * 9 + j] : 0.f;
}

// ---------------------------------------------------------------------------
// conv2 (50->50) + relu + pool. h1:[nimg,8480] -> h2:[nimg,1280] (pads zeroed)
// Block per image, thread = 5 oc x 1 pooled pos. Weights from w2p via
// ds_read_b128, double-buffered 4-ic chunks. (r8-proven, 318 us)
// ---------------------------------------------------------------------------
__global__ __launch_bounds__(256) void conv2_pool(
    const float* __restrict__ h1, const float* __restrict__ w2p,
    const float* __restrict__ b2, float* __restrict__ h2)
{
    __shared__ float in[8450];
    __shared__ __align__(16) float wbuf[2][2400];   // [buf][icl*600 + oc*12 + j]
    const int b = blockIdx.x;
    const int t = threadIdx.x;
    for (int i = t; i < 8450; i += 256) in[i] = h1[(size_t)b * 8480 + i];
    {   // stage ic 0..3 (2400 floats = 600 float4)
        const float4* src = (const float4*)w2p;
        float4* dst = (float4*)wbuf[0];
        for (int s = t; s < 600; s += 256) dst[s] = src[s];
    }
    __syncthreads();
    if (t < 30) h2[(size_t)b * 1280 + 1250 + t] = 0.f;       // zero pad cols

    const int ocg = t / 25;
    const int pos = t % 25;
    const int py = pos / 5, px = pos % 5;
    const int oc0 = ocg * 5;
    const bool act = (t < 250);

    float acc[5][4];
#pragma unroll
    for (int j = 0; j < 5; ++j)
#pragma unroll
        for (int q = 0; q < 4; ++q) acc[j][q] = 0.f;

    const float* ib = &in[(2 * py) * 13 + 2 * px];

    for (int ic0 = 0; ic0 < 50; ic0 += 4) {
        const int cur = (ic0 >> 2) & 1;
        if (ic0 + 4 < 50) {           // prefetch next <=4-ic weight chunk
            const int nxt = cur ^ 1;
            const int nic2 = (50 - ic0 - 4 < 4) ? (50 - ic0 - 4) : 4;
            const float4* src = (const float4*)(w2p + (size_t)(ic0 + 4) * 600);
            float4* dst = (float4*)wbuf[nxt];
            for (int s = t; s < nic2 * 150; s += 256) dst[s] = src[s];
        }
        if (act) {
            const int nic = (50 - ic0 < 4) ? (50 - ic0) : 4;
            for (int icl = 0; icl < nic; ++icl) {
                const int ic = ic0 + icl;
                float p[4][4];
                const float* ip = ib + ic * 169;
#pragma unroll
                for (int r = 0; r < 4; ++r)
#pragma unroll
                    for (int c = 0; c < 4; ++c) p[r][c] = ip[r * 13 + c];
                const float* wl = &wbuf[cur][icl * 600 + oc0 * 12];
#pragma unroll
                for (int j = 0; j < 5; ++j) {
                    const f32x4 wv0 = *(const f32x4*)(wl + j * 12);
                    const f32x4 wv1 = *(const f32x4*)(wl + j * 12 + 4);
                    const f32x4 wv2 = *(const f32x4*)(wl + j * 12 + 8);
                    const float w00 = wv0[0], w01 = wv0[1], w02 = wv0[2];
                    const float w10 = wv0[3], w11 = wv1[0], w12 = wv1[1];
                    const float w20 = wv1[2], w21 = wv1[3], w22 = wv2[0];
#pragma unroll
                    for (int dy = 0; dy < 2; ++dy)
#pragma unroll
                        for (int dx = 0; dx < 2; ++dx) {
                            acc[j][dy * 2 + dx] +=
                                  p[dy + 0][dx + 0] * w00 + p[dy + 0][dx + 1] * w01 + p[dy + 0][dx + 2] * w02
                                + p[dy + 1][dx + 0] * w10 + p[dy + 1][dx + 1] * w11 + p[dy + 1][dx + 2] * w12
                                + p[dy + 2][dx + 0] * w20 + p[dy + 2][dx + 1] * w21 + p[dy + 2][dx + 2] * w22;
                        }
                }
            }
        }
        __syncthreads();
    }

    if (act) {
#pragma unroll
        for (int j = 0; j < 5; ++j) {
            float v = fmaxf(fmaxf(acc[j][0], acc[j][1]), fmaxf(acc[j][2], acc[j][3]));
            h2[(size_t)b * 1280 + (oc0 + j) * 25 + pos] = fmaxf(v + b2[oc0 + j], 0.f);
        }
    }
}

// ---------------------------------------------------------------------------
// conv3 (50->50 on 5x5) + relu + pool -> f3:[nimg,50]. 4 images per block.
// ---------------------------------------------------------------------------
__global__ __launch_bounds__(256) void conv3_pool(
    const float* __restrict__ h2, const float* __restrict__ w3,
    const float* __restrict__ b3, float* __restrict__ f3)
{
    __shared__ float in[5000];
    const int blk = blockIdx.x;
    const int t = threadIdx.x;
    for (int i = t; i < 5000; i += 256) {
        const int img = i / 1250, off = i % 1250;
        in[i] = h2[(size_t)(blk * 4 + img) * 1280 + off];
    }
    __syncthreads();
    const int il = t >> 6;
    const int oc = t & 63;
    if (oc >= 50) return;

    const float* ip0 = &in[il * 1250];
    float a00 = 0.f, a01 = 0.f, a10 = 0.f, a11 = 0.f;
    for (int ic = 0; ic < 50; ++ic) {
        float p[4][4];
        const float* ip = ip0 + ic * 25;
#pragma unroll
        for (int r = 0; r < 4; ++r)
#pragma unroll
            for (int c = 0; c < 4; ++c) p[r][c] = ip[r * 5 + c];
        const float* wp = &w3[((size_t)oc * 50 + ic) * 9];
        const float w00 = wp[0], w01 = wp[1], w02 = wp[2];
        const float w10 = wp[3], w11 = wp[4], w12 = wp[5];
        const float w20 = wp[6], w21 = wp[7], w22 = wp[8];
        a00 += p[0][0]*w00 + p[0][1]*w01 + p[0][2]*w02 + p[1][0]*w10 + p[1][1]*w11 + p[1][2]*w12 + p[2][0]*w20 + p[2][1]*w21 + p[2][2]*w22;
        a01 += p[0][1]*w00 + p[0][2]*w01 + p[0][3]*w02 + p[1][1]*w10 + p[1][2]*w11 + p[1][3]*w12 + p[2][1]*w20 + p[2][2]*w21 + p[2][3]*w22;
        a10 += p[1][0]*w00 + p[1][1]*w01 + p[1][2]*w02 + p[2][0]*w10 + p[2][1]*w11 + p[2][2]*w12 + p[3][0]*w20 + p[3][1]*w21 + p[3][2]*w22;
        a11 += p[1][1]*w00 + p[1][2]*w01 + p[1][3]*w02 + p[2][1]*w10 + p[2][2]*w11 + p[2][3]*w12 + p[3][1]*w20 + p[3][2]*w21 + p[3][3]*w22;
    }
    float v = fmaxf(fmaxf(a00, a01), fmaxf(a10, a11)) + b3[oc];
    f3[(size_t)(blk * 4 + il) * 50 + oc] = fmaxf(v, 0.f);
}

// ---------------------------------------------------------------------------
// exit: z = f @ dw^T + db (2 outputs); e[b] = (z0 >= z1). fp32, block/sample.
// ---------------------------------------------------------------------------
__global__ __launch_bounds__(256) void exit_kernel(
    const float* __restrict__ F, int ldf, int K,
    const float* __restrict__ dw, const float* __restrict__ db, int* __restrict__ e)
{
    const int b = blockIdx.x;
    const int t = threadIdx.x;
    const float* f = F + (size_t)b * ldf;
    float s0 = 0.f, s1 = 0.f;
    for (int i = t; i < K; i += 256) {
        const float v = f[i];
        s0 += v * dw[i];
        s1 += v * dw[K + i];
    }
    __shared__ float r0[256];
    __shared__ float r1[256];
    r0[t] = s0; r1[t] = s1;
    __syncthreads();
    for (int s = 128; s > 0; s >>= 1) {
        if (t < s) { r0[t] += r0[t + s]; r1[t] += r1[t + s]; }
        __syncthreads();
    }
    if (t == 0) e[b] = (r0[0] + db[0] >= r1[0] + db[1]) ? 1 : 0;
}

// ---------------------------------------------------------------------------
// fp32 [N,K] -> bf16 [Np,Kp], zero-padded.
// ---------------------------------------------------------------------------
__global__ __launch_bounds__(256) void w_to_bf16(
    const float* __restrict__ src, bf16_t* __restrict__ dst, int N, int K, int Kp, int total)
{
    const int idx = blockIdx.x * 256 + threadIdx.x;
    if (idx >= total) return;
    const int n = idx / Kp, k = idx % Kp;
    const float v = (n < N && k < K) ? src[(size_t)n * K + k] : 0.f;
    dst[idx] = (bf16_t)v;
}

// ---------------------------------------------------------------------------
// MFMA GEMM, split-K=2: z=0 covers k [0,khalf) -> C0 (with bias),
// z=1 covers [khalf,Kp) -> C1 (no bias). BM=128, BN=64, BK=32, LDS stride 40.
// ---------------------------------------------------------------------------
__global__ __launch_bounds__(256) void gemm_f32a_bf16w(
    const float* __restrict__ A, int lda,
    const bf16_t* __restrict__ W,
    const float* __restrict__ bias, float* __restrict__ C0, float* __restrict__ C1,
    int Kp, int khalf, int Nout, int ldc)
{
    __shared__ __align__(16) bf16_t As[128 * 40];
    __shared__ __align__(16) bf16_t Bs[64 * 40];

    const int t = threadIdx.x;
    const int m0 = blockIdx.x * 128;
    const int n0 = blockIdx.y * 64;
    const int kz = blockIdx.z;
    const int kbeg = kz ? khalf : 0;
    const int kend = kz ? Kp : khalf;
    float* C = kz ? C1 : C0;

    const int wave = t >> 6;
    const int lane = t & 63;
    const int wm = (wave >> 1) * 64;
    const int wn = (wave & 1) * 32;
    const int quad = lane >> 4;
    const int lr = lane & 15;

    f32x4 acc[4][2];
#pragma unroll
    for (int i = 0; i < 4; ++i)
#pragma unroll
        for (int j = 0; j < 2; ++j) acc[i][j] = (f32x4)0.f;

    const int ar = t >> 2;          // 0..63
    const int ac = (t & 3) * 8;     // 0,8,16,24

    for (int k0 = kbeg; k0 < kend; k0 += 32) {
        __syncthreads();
#pragma unroll
        for (int h = 0; h < 2; ++h) {
            const float* ap = A + (size_t)(m0 + ar + h * 64) * lda + k0 + ac;
            const float4 f0 = *(const float4*)ap;
            const float4 f1 = *(const float4*)(ap + 4);
            bf16x8 v;
            v[0] = (bf16_t)f0.x; v[1] = (bf16_t)f0.y; v[2] = (bf16_t)f0.z; v[3] = (bf16_t)f0.w;
            v[4] = (bf16_t)f1.x; v[5] = (bf16_t)f1.y; v[6] = (bf16_t)f1.z; v[7] = (bf16_t)f1.w;
            *(bf16x8*)&As[(ar + h * 64) * 40 + ac] = v;
        }
        *(uint4*)&Bs[ar * 40 + ac] = *(const uint4*)&W[(size_t)(n0 + ar) * Kp + k0 + ac];
        __syncthreads();

        bf16x8 af[4], bfr[2];
#pragma unroll
        for (int i = 0; i < 4; ++i)
            af[i] = *(const bf16x8*)&As[(wm + i * 16 + lr) * 40 + quad * 8];
#pragma unroll
        for (int j = 0; j < 2; ++j)
            bfr[j] = *(const bf16x8*)&Bs[(wn + j * 16 + lr) * 40 + quad * 8];
#pragma unroll
        for (int i = 0; i < 4; ++i)
#pragma unroll
            for (int j = 0; j < 2; ++j)
                acc[i][j] = __builtin_amdgcn_mfma_f32_16x16x32_bf16(af[i], bfr[j], acc[i][j], 0, 0, 0);
    }

#pragma unroll
    for (int j = 0; j < 2; ++j) {
        const int n = n0 + wn + j * 16 + lr;
        const float bv = (kz == 0 && n < Nout) ? bias[n] : 0.f;
#pragma unroll
        for (int i = 0; i < 4; ++i) {
            const int mrow = m0 + wm + i * 16 + quad * 4;
#pragma unroll
            for (int r = 0; r < 4; ++r)
                C[(size_t)(mrow + r) * ldc + n] = acc[i][j][r] + bv;
        }
    }
}

// ---------------------------------------------------------------------------
// out[b,o<10] = (U[b,:500]+U2[b,:500]) @ W[o,:500] + bias[o]. U2 may be null.
// Block: 256 thr = 16 images x 16 k-strips (lane-adjacent = k, coalesced).
// ---------------------------------------------------------------------------
__global__ __launch_bounds__(256) void lin10(
    const float* __restrict__ U, const float* __restrict__ U2, int ldu,
    const float* __restrict__ W, const float* __restrict__ bias,
    float* __restrict__ out)
{
    __shared__ float red[16][10][17];
    const int t = threadIdx.x;
    const int ks = t & 15;
    const int il = t >> 4;
    const int b  = blockIdx.x * 16 + il;
    const float* u = U + (size_t)b * ldu;

    float acc[10];
#pragma unroll
    for (int o = 0; o < 10; ++o) acc[o] = 0.f;

    if (U2) {
        const float* u2 = U2 + (size_t)b * ldu;
        for (int i = 0; i < 31; ++i) {
            const int k = ks + i * 16;
            const float uv = u[k] + u2[k];
#pragma unroll
            for (int o = 0; o < 10; ++o) acc[o] += uv * W[o * 500 + k];
        }
        const int k = ks + 496;
        if (k < 500) {
            const float uv = u[k] + u2[k];
#pragma unroll
            for (int o = 0; o < 10; ++o) acc[o] += uv * W[o * 500 + k];
        }
    } else {
        for (int i = 0; i < 31; ++i) {
            const int k = ks + i * 16;
            const float uv = u[k];
#pragma unroll
            for (int o = 0; o < 10; ++o) acc[o] += uv * W[o * 500 + k];
        }
        const int k = ks + 496;
        if (k < 500) {
            const float uv = u[k];
#pragma unroll
            for (int o = 0; o < 10; ++o) acc[o] += uv * W[o * 500 + k];
        }
    }
#pragma unroll
    for (int o = 0; o < 10; ++o) red[il][o][ks] = acc[o];
    __syncthreads();
    if (t < 160) {
        const int il2 = t / 10, o = t - il2 * 10;
        float s = 0.f;
#pragma unroll
        for (int q = 0; q < 16; ++q) s += red[il2][o][q];
        out[(size_t)(blockIdx.x * 16 + il2) * 10 + o] = s + bias[o];
    }
}

// ---------------------------------------------------------------------------
// u3[b,o<500] = relu(f3[b,:50] @ l1w[o,:50] + l1b[o]); u3 row stride 512.
// ---------------------------------------------------------------------------
__global__ __launch_bounds__(256) void lin500(
    const float* __restrict__ f3, const float* __restrict__ w,
    const float* __restrict__ bias, float* __restrict__ u3)
{
    __shared__ float fs[50];
    const int b = blockIdx.x;
    const int t = threadIdx.x;
    if (t < 50) fs[t] = f3[(size_t)b * 50 + t];
    __syncthreads();
    for (int o = t; o < 500; o += 256) {
        float s = 0.f;
#pragma unroll
        for (int k = 0; k < 50; ++k) s += fs[k] * w[o * 50 + k];
        u3[(size_t)b * 512 + o] = fmaxf(s + bias[o], 0.f);
    }
}

// ---------------------------------------------------------------------------
// select per exits, log_softmax over 10, write final output (full batch).
// ---------------------------------------------------------------------------
__global__ __launch_bounds__(256) void final_select(
    const int* __restrict__ e1, const int* __restrict__ e2,
    const float* __restrict__ o1, const float* __restrict__ o2,
    const float* __restrict__ o3, float* __restrict__ out)
{
    const int b = blockIdx.x * 256 + threadIdx.x;
    if (b >= B_IMG) return;
    const float* src = e1[b] ? o1 : (e2[b] ? o2 : o3);
    src += (size_t)b * 10;
    float v[10];
    float m = -3.4e38f;
#pragma unroll
    for (int o = 0; o < 10; ++o) { v[o] = src[o]; m = fmaxf(m, v[o]); }
    float s = 0.f;
#pragma unroll
    for (int o = 0; o < 10; ++o) s += expf(v[o] - m);
    const float ls = logf(s);
#pragma unroll
    for (int o = 0; o < 10; ++o) out[(size_t)b * 10 + o] = v[o] - m - ls;
}

// ---------------------------------------------------------------------------
static inline size_t align256(size_t v) { return (v + 255) & ~(size_t)255; }

extern "C" void kernel_launch(void* const* d_in, const int* in_sizes, int n_in,
                              void* d_out, int out_size, void* d_ws, size_t ws_size,
                              hipStream_t stream)
{
    const float* x     = (const float*)d_in[0];
    const float* c1w   = (const float*)d_in[1];
    const float* c1b   = (const float*)d_in[2];
    const float* c2w   = (const float*)d_in[3];
    const float* c2b   = (const float*)d_in[4];
    const float* c3w   = (const float*)d_in[5];
    const float* c3b   = (const float*)d_in[6];
    const float* l1c1w = (const float*)d_in[7];
    const float* l1c1b = (const float*)d_in[8];
    const float* l2c1w = (const float*)d_in[9];
    const float* l2c1b = (const float*)d_in[10];
    const float* l1c2w = (const float*)d_in[11];
    const float* l1c2b = (const float*)d_in[12];
    const float* l2c2w = (const float*)d_in[13];
    const float* l2c2b = (const float*)d_in[14];
    const float* l1w   = (const float*)d_in[15];
    const float* l1b   = (const float*)d_in[16];
    const float* l2w   = (const float*)d_in[17];
    const float* l2b   = (const float*)d_in[18];
    const float* d1w   = (const float*)d_in[19];
    const float* d1b   = (const float*)d_in[20];
    const float* d2w   = (const float*)d_in[21];
    const float* d2b   = (const float*)d_in[22];

    // ---- persistent layout (full batch) ----
    size_t off = 0;
    const size_t oWb1  = off; off = align256(off + (size_t)512 * 8480 * 2);
    const size_t oWb2  = off; off = align256(off + (size_t)512 * 1280 * 2);
    const size_t oW2P  = off; off = align256(off + (size_t)50 * 600 * 4);
    const size_t oOut1 = off; off = align256(off + (size_t)B_IMG * 10 * 4);
    const size_t oOut2 = off; off = align256(off + (size_t)B_IMG * 10 * 4);
    const size_t oOut3 = off; off = align256(off + (size_t)B_IMG * 10 * 4);
    const size_t oE1   = off; off = align256(off + (size_t)B_IMG * 4);
    const size_t oE2   = off; off = align256(off + (size_t)B_IMG * 4);
    const size_t persist = off;

    // ---- per-chunk bytes: h1 + h2 + u + upart + f3 ----
    auto chunk_bytes = [](int C) {
        size_t s = 0;
        s += align256((size_t)C * 8480 * 4);   // h1
        s += align256((size_t)C * 1280 * 4);   // h2
        s += align256((size_t)C * 512 * 4);    // u
        s += align256((size_t)C * 512 * 4);    // upart (split-K part 1)
        s += align256((size_t)C * 50 * 4);     // f3
        return s;
    };
    int C = B_IMG;
    while (C > 256 && persist + chunk_bytes(C) > ws_size) C >>= 1;

    char* ws = (char*)d_ws;
    bf16_t* Wb1  = (bf16_t*)(ws + oWb1);
    bf16_t* Wb2  = (bf16_t*)(ws + oWb2);
    float*  w2p  = (float*) (ws + oW2P);
    float*  out1 = (float*) (ws + oOut1);
    float*  out2 = (float*) (ws + oOut2);
    float*  out3 = (float*) (ws + oOut3);
    int*    e1   = (int*)   (ws + oE1);
    int*    e2   = (int*)   (ws + oE2);

    size_t co = persist;
    float* h1 = (float*)(ws + co); co += align256((size_t)C * 8480 * 4);
    float* h2 = (float*)(ws + co); co += align256((size_t)C * 1280 * 4);
    float* u  = (float*)(ws + co); co += align256((size_t)C * 512 * 4);
    float* up = (float*)(ws + co); co += align256((size_t)C * 512 * 4);
    float* f3 = (float*)(ws + co); co += align256((size_t)C * 50 * 4);

    float* out = (float*)d_out;

    // weight conversion (once)
    w_to_bf16<<<(512 * 8480) / 256, 256, 0, stream>>>(l1c1w, Wb1, 500, 8450, 8480, 512 * 8480);
    w_to_bf16<<<(512 * 1280) / 256, 256, 0, stream>>>(l1c2w, Wb2, 500, 1250, 1280, 512 * 1280);
    w2_transpose<<<(50 * 600 + 255) / 256, 256, 0, stream>>>(c2w, w2p);

    for (int b0 = 0; b0 < B_IMG; b0 += C) {
        // stage 1
        conv1_pool<<<(C * 169 + 255) / 256, 256, 0, stream>>>(x + (size_t)b0 * 784, c1w, c1b, h1, C);
        exit_kernel<<<C, 256, 0, stream>>>(h1, 8480, 8450, d1w, d1b, e1 + b0);
        gemm_f32a_bf16w<<<dim3(C / 128, 8, 2), 256, 0, stream>>>(h1, 8480, Wb1, l1c1b, u, up, 8480, 4256, 500, 512);
        lin10<<<C / 16, 256, 0, stream>>>(u, up, 512, l2c1w, l2c1b, out1 + (size_t)b0 * 10);

        // stage 2
        conv2_pool<<<C, 256, 0, stream>>>(h1, w2p, c2b, h2);
        exit_kernel<<<C, 256, 0, stream>>>(h2, 1280, 1250, d2w, d2b, e2 + b0);
        gemm_f32a_bf16w<<<dim3(C / 128, 8, 2), 256, 0, stream>>>(h2, 1280, Wb2, l1c2b, u, up, 1280, 640, 500, 512);
        lin10<<<C / 16, 256, 0, stream>>>(u, up, 512, l2c2w, l2c2b, out2 + (size_t)b0 * 10);

        // stage 3
        conv3_pool<<<C / 4, 256, 0, stream>>>(h2, c3w, c3b, f3);
        lin500<<<C, 256, 0, stream>>>(f3, l1w, l1b, u);
        lin10<<<C / 16, 256, 0, stream>>>(u, nullptr, 512, l2w, l2b, out3 + (size_t)b0 * 10);
    }

    final_select<<<B_IMG / 256, 256, 0, stream>>>(e1, e2, out1, out2, out3, out);

    (void)in_sizes; (void)n_in; (void)out_size; (void)ws_size;
}

// Round 10
// 740.795 us; speedup vs baseline: 2.2750x; 1.0476x over previous
//
#include <hip/hip_runtime.h>
#include <hip/hip_bf16.h>
#include <cstdint>

// ---------------------------------------------------------------------------
// ThreeLayerCNN (BranchyNet early-exit), B=4096.
// Precision: conv1/conv2/exit1/exit2 fp32 (argmax parity with numpy ref);
// big FC GEMMs (l1c1, l1c2) bf16 MFMA w/ fp32 accum (output tol 0.146).
// Round 10: block-role MEGA-FUSION (m114: MFMA/VALU waves co-schedule):
//   P: conv1 | wb16(Wb1) | wb16(Wb2) | w2_transpose
//   A: gemm1(split-K) | conv2 | exit1        (all consume h1 only)
//   C: gemm2->v/vp | conv3 | lin10-1 | exit2 (all consume h2 / stage1-u)
//   D: lin10-2 | lin500->u3,  E: lin10-3,  F: final_select
// gemm2/lin500 outputs live in the dead h1 region (no extra workspace).
// All FP expression trees identical to round 9.
// ---------------------------------------------------------------------------

typedef __bf16 bf16_t;
typedef __bf16 bf16x8 __attribute__((ext_vector_type(8)));
typedef float  f32x4  __attribute__((ext_vector_type(4)));

#define B_IMG 4096

// ======================= role bodies (device functions) =====================

__device__ void role_conv1(char* smem, int blk,
    const float* __restrict__ x, const float* __restrict__ w1,
    const float* __restrict__ b1, float* __restrict__ h1)
{
    float* ws = (float*)smem;        // 450
    float* bs = ws + 456;            // 50
    const int t = threadIdx.x;
    for (int i = t; i < 450; i += 256) ws[i] = w1[i];
    if (t < 50) bs[t] = b1[t];
    __syncthreads();

    const int idx = blk * 256 + t;
    if (idx >= B_IMG * 169) return;
    const int b   = idx / 169;
    const int pos = idx % 169;
    const int py = pos / 13, px = pos % 13;

    const float* xp = x + (size_t)b * 784 + (2 * py) * 28 + 2 * px;
    float p[4][4];
#pragma unroll
    for (int r = 0; r < 4; ++r)
#pragma unroll
        for (int c = 0; c < 4; ++c) p[r][c] = xp[r * 28 + c];

    float* hb = h1 + (size_t)b * 8480 + pos;
    if (pos < 30) h1[(size_t)b * 8480 + 8450 + pos] = 0.f;   // zero pad cols

    for (int oc = 0; oc < 50; ++oc) {
        const float* wp = &ws[oc * 9];
        const float w00 = wp[0], w01 = wp[1], w02 = wp[2];
        const float w10 = wp[3], w11 = wp[4], w12 = wp[5];
        const float w20 = wp[6], w21 = wp[7], w22 = wp[8];
        float a[2][2];
#pragma unroll
        for (int dy = 0; dy < 2; ++dy)
#pragma unroll
            for (int dx = 0; dx < 2; ++dx) {
                a[dy][dx] = p[dy + 0][dx + 0] * w00 + p[dy + 0][dx + 1] * w01 + p[dy + 0][dx + 2] * w02
                          + p[dy + 1][dx + 0] * w10 + p[dy + 1][dx + 1] * w11 + p[dy + 1][dx + 2] * w12
                          + p[dy + 2][dx + 0] * w20 + p[dy + 2][dx + 1] * w21 + p[dy + 2][dx + 2] * w22;
            }
        float v = fmaxf(fmaxf(a[0][0], a[0][1]), fmaxf(a[1][0], a[1][1])) + bs[oc];
        hb[oc * 169] = fmaxf(v, 0.f);
    }
}

__device__ void role_wb16(int blk, const float* __restrict__ src,
                          bf16_t* __restrict__ dst, int N, int K, int Kp, int total)
{
    const int idx = blk * 256 + threadIdx.x;
    if (idx >= total) return;
    const int n = idx / Kp, k = idx % Kp;
    const float v = (n < N && k < K) ? src[(size_t)n * K + k] : 0.f;
    dst[idx] = (bf16_t)v;
}

__device__ void role_w2t(int blk, const float* __restrict__ w2, float* __restrict__ w2p)
{
    const int idx = blk * 256 + threadIdx.x;
    if (idx >= 50 * 600) return;
    const int ic = idx / 600, r = idx % 600, oc = r / 12, j = r % 12;
    w2p[idx] = (j < 9) ? w2[oc * 450 + ic * 9 + j] : 0.f;
}

// conv2 (50->50) + relu + pool; block per image, thread = 5 oc x 1 pooled pos.
// smem: in[8452] then wbuf[2][2400] (16B-aligned at 8452*4=33808).
__device__ void role_conv2(char* smem, int b,
    const float* __restrict__ h1, const float* __restrict__ w2p,
    const float* __restrict__ b2, float* __restrict__ h2)
{
    float* in   = (float*)smem;
    float* wbuf = in + 8452;
    const int t = threadIdx.x;
    for (int i = t; i < 8450; i += 256) in[i] = h1[(size_t)b * 8480 + i];
    {
        const float4* src = (const float4*)w2p;
        float4* dst = (float4*)wbuf;
        for (int s = t; s < 600; s += 256) dst[s] = src[s];
    }
    __syncthreads();
    if (t < 30) h2[(size_t)b * 1280 + 1250 + t] = 0.f;

    const int ocg = t / 25;
    const int pos = t % 25;
    const int py = pos / 5, px = pos % 5;
    const int oc0 = ocg * 5;
    const bool act = (t < 250);

    float acc[5][4];
#pragma unroll
    for (int j = 0; j < 5; ++j)
#pragma unroll
        for (int q = 0; q < 4; ++q) acc[j][q] = 0.f;

    const float* ib = &in[(2 * py) * 13 + 2 * px];

    for (int ic0 = 0; ic0 < 50; ic0 += 4) {
        const int cur = (ic0 >> 2) & 1;
        if (ic0 + 4 < 50) {
            const int nxt = cur ^ 1;
            const int nic2 = (50 - ic0 - 4 < 4) ? (50 - ic0 - 4) : 4;
            const float4* src = (const float4*)(w2p + (size_t)(ic0 + 4) * 600);
            float4* dst = (float4*)(wbuf + nxt * 2400);
            for (int s = t; s < nic2 * 150; s += 256) dst[s] = src[s];
        }
        if (act) {
            const int nic = (50 - ic0 < 4) ? (50 - ic0) : 4;
            for (int icl = 0; icl < nic; ++icl) {
                const int ic = ic0 + icl;
                float p[4][4];
                const float* ip = ib + ic * 169;
#pragma unroll
                for (int r = 0; r < 4; ++r)
#pragma unroll
                    for (int c = 0; c < 4; ++c) p[r][c] = ip[r * 13 + c];
                const float* wl = wbuf + cur * 2400 + icl * 600 + oc0 * 12;
#pragma unroll
                for (int j = 0; j < 5; ++j) {
                    const f32x4 wv0 = *(const f32x4*)(wl + j * 12);
                    const f32x4 wv1 = *(const f32x4*)(wl + j * 12 + 4);
                    const f32x4 wv2 = *(const f32x4*)(wl + j * 12 + 8);
                    const float w00 = wv0[0], w01 = wv0[1], w02 = wv0[2];
                    const float w10 = wv0[3], w11 = wv1[0], w12 = wv1[1];
                    const float w20 = wv1[2], w21 = wv1[3], w22 = wv2[0];
#pragma unroll
                    for (int dy = 0; dy < 2; ++dy)
#pragma unroll
                        for (int dx = 0; dx < 2; ++dx) {
                            acc[j][dy * 2 + dx] +=
                                  p[dy + 0][dx + 0] * w00 + p[dy + 0][dx + 1] * w01 + p[dy + 0][dx + 2] * w02
                                + p[dy + 1][dx + 0] * w10 + p[dy + 1][dx + 1] * w11 + p[dy + 1][dx + 2] * w12
                                + p[dy + 2][dx + 0] * w20 + p[dy + 2][dx + 1] * w21 + p[dy + 2][dx + 2] * w22;
                        }
                }
            }
        }
        __syncthreads();
    }

    if (act) {
#pragma unroll
        for (int j = 0; j < 5; ++j) {
            float v = fmaxf(fmaxf(acc[j][0], acc[j][1]), fmaxf(acc[j][2], acc[j][3]));
            h2[(size_t)b * 1280 + (oc0 + j) * 25 + pos] = fmaxf(v + b2[oc0 + j], 0.f);
        }
    }
}

__device__ void role_conv3(char* smem, int blk,
    const float* __restrict__ h2, const float* __restrict__ w3,
    const float* __restrict__ b3, float* __restrict__ f3)
{
    float* in = (float*)smem;    // 5000
    const int t = threadIdx.x;
    for (int i = t; i < 5000; i += 256) {
        const int img = i / 1250, off = i % 1250;
        in[i] = h2[(size_t)(blk * 4 + img) * 1280 + off];
    }
    __syncthreads();
    const int il = t >> 6;
    const int oc = t & 63;
    if (oc >= 50) return;

    const float* ip0 = &in[il * 1250];
    float a00 = 0.f, a01 = 0.f, a10 = 0.f, a11 = 0.f;
    for (int ic = 0; ic < 50; ++ic) {
        float p[4][4];
        const float* ip = ip0 + ic * 25;
#pragma unroll
        for (int r = 0; r < 4; ++r)
#pragma unroll
            for (int c = 0; c < 4; ++c) p[r][c] = ip[r * 5 + c];
        const float* wp = &w3[((size_t)oc * 50 + ic) * 9];
        const float w00 = wp[0], w01 = wp[1], w02 = wp[2];
        const float w10 = wp[3], w11 = wp[4], w12 = wp[5];
        const float w20 = wp[6], w21 = wp[7], w22 = wp[8];
        a00 += p[0][0]*w00 + p[0][1]*w01 + p[0][2]*w02 + p[1][0]*w10 + p[1][1]*w11 + p[1][2]*w12 + p[2][0]*w20 + p[2][1]*w21 + p[2][2]*w22;
        a01 += p[0][1]*w00 + p[0][2]*w01 + p[0][3]*w02 + p[1][1]*w10 + p[1][2]*w11 + p[1][3]*w12 + p[2][1]*w20 + p[2][2]*w21 + p[2][3]*w22;
        a10 += p[1][0]*w00 + p[1][1]*w01 + p[1][2]*w02 + p[2][0]*w10 + p[2][1]*w11 + p[2][2]*w12 + p[3][0]*w20 + p[3][1]*w21 + p[3][2]*w22;
        a11 += p[1][1]*w00 + p[1][2]*w01 + p[1][3]*w02 + p[2][1]*w10 + p[2][2]*w11 + p[2][3]*w12 + p[3][1]*w20 + p[3][2]*w21 + p[3][3]*w22;
    }
    float v = fmaxf(fmaxf(a00, a01), fmaxf(a10, a11)) + b3[oc];
    f3[(size_t)(blk * 4 + il) * 50 + oc] = fmaxf(v, 0.f);
}

__device__ void role_exit(char* smem, int b,
    const float* __restrict__ F, int ldf, int K,
    const float* __restrict__ dw, const float* __restrict__ db, int* __restrict__ e)
{
    float* r0 = (float*)smem;   // 256
    float* r1 = r0 + 256;       // 256
    const int t = threadIdx.x;
    const float* f = F + (size_t)b * ldf;
    float s0 = 0.f, s1 = 0.f;
    for (int i = t; i < K; i += 256) {
        const float v = f[i];
        s0 += v * dw[i];
        s1 += v * dw[K + i];
    }
    r0[t] = s0; r1[t] = s1;
    __syncthreads();
    for (int s = 128; s > 0; s >>= 1) {
        if (t < s) { r0[t] += r0[t + s]; r1[t] += r1[t + s]; }
        __syncthreads();
    }
    if (t == 0) e[b] = (r0[0] + db[0] >= r1[0] + db[1]) ? 1 : 0;
}

// MFMA GEMM split-K=2 (r9-proven). g in [0,512): bx=g&31, by=(g>>5)&7, kz=g>>8.
__device__ void role_gemm(char* smem, int g,
    const float* __restrict__ A, int lda, const bf16_t* __restrict__ W,
    const float* __restrict__ bias, float* __restrict__ C0, float* __restrict__ C1,
    int Kp, int khalf, int Nout, int ldc)
{
    bf16_t* As = (bf16_t*)smem;      // 128*40
    bf16_t* Bs = As + 128 * 40;      // 64*40

    const int t = threadIdx.x;
    const int m0 = (g & 31) * 128;
    const int n0 = ((g >> 5) & 7) * 64;
    const int kz = g >> 8;
    const int kbeg = kz ? khalf : 0;
    const int kend = kz ? Kp : khalf;
    float* C = kz ? C1 : C0;

    const int wave = t >> 6;
    const int lane = t & 63;
    const int wm = (wave >> 1) * 64;
    const int wn = (wave & 1) * 32;
    const int quad = lane >> 4;
    const int lr = lane & 15;

    f32x4 acc[4][2];
#pragma unroll
    for (int i = 0; i < 4; ++i)
#pragma unroll
        for (int j = 0; j < 2; ++j) acc[i][j] = (f32x4)0.f;

    const int ar = t >> 2;
    const int ac = (t & 3) * 8;

    for (int k0 = kbeg; k0 < kend; k0 += 32) {
        __syncthreads();
#pragma unroll
        for (int h = 0; h < 2; ++h) {
            const float* ap = A + (size_t)(m0 + ar + h * 64) * lda + k0 + ac;
            const float4 f0 = *(const float4*)ap;
            const float4 f1 = *(const float4*)(ap + 4);
            bf16x8 v;
            v[0] = (bf16_t)f0.x; v[1] = (bf16_t)f0.y; v[2] = (bf16_t)f0.z; v[3] = (bf16_t)f0.w;
            v[4] = (bf16_t)f1.x; v[5] = (bf16_t)f1.y; v[6] = (bf16_t)f1.z; v[7] = (bf16_t)f1.w;
            *(bf16x8*)&As[(ar + h * 64) * 40 + ac] = v;
        }
        *(uint4*)&Bs[ar * 40 + ac] = *(const uint4*)&W[(size_t)(n0 + ar) * Kp + k0 + ac];
        __syncthreads();

        bf16x8 af[4], bfr[2];
#pragma unroll
        for (int i = 0; i < 4; ++i)
            af[i] = *(const bf16x8*)&As[(wm + i * 16 + lr) * 40 + quad * 8];
#pragma unroll
        for (int j = 0; j < 2; ++j)
            bfr[j] = *(const bf16x8*)&Bs[(wn + j * 16 + lr) * 40 + quad * 8];
#pragma unroll
        for (int i = 0; i < 4; ++i)
#pragma unroll
            for (int j = 0; j < 2; ++j)
                acc[i][j] = __builtin_amdgcn_mfma_f32_16x16x32_bf16(af[i], bfr[j], acc[i][j], 0, 0, 0);
    }

#pragma unroll
    for (int j = 0; j < 2; ++j) {
        const int n = n0 + wn + j * 16 + lr;
        const float bv = (kz == 0 && n < Nout) ? bias[n] : 0.f;
#pragma unroll
        for (int i = 0; i < 4; ++i) {
            const int mrow = m0 + wm + i * 16 + quad * 4;
#pragma unroll
            for (int r = 0; r < 4; ++r)
                C[(size_t)(mrow + r) * ldc + n] = acc[i][j][r] + bv;
        }
    }
}

// lin10: out[b,o<10] = (U[+U2]) @ W^T + bias; 16 img x 16 k-strips per block.
__device__ void role_lin10(char* smem, int blk,
    const float* __restrict__ U, const float* __restrict__ U2, int ldu,
    const float* __restrict__ W, const float* __restrict__ bias,
    float* __restrict__ out)
{
    float* red = (float*)smem;   // [16][10][17]
    const int t = threadIdx.x;
    const int ks = t & 15;
    const int il = t >> 4;
    const int b  = blk * 16 + il;
    const float* u = U + (size_t)b * ldu;

    float acc[10];
#pragma unroll
    for (int o = 0; o < 10; ++o) acc[o] = 0.f;

    if (U2) {
        const float* u2 = U2 + (size_t)b * ldu;
        for (int i = 0; i < 31; ++i) {
            const int k = ks + i * 16;
            const float uv = u[k] + u2[k];
#pragma unroll
            for (int o = 0; o < 10; ++o) acc[o] += uv * W[o * 500 + k];
        }
        const int k = ks + 496;
        if (k < 500) {
            const float uv = u[k] + u2[k];
#pragma unroll
            for (int o = 0; o < 10; ++o) acc[o] += uv * W[o * 500 + k];
        }
    } else {
        for (int i = 0; i < 31; ++i) {
            const int k = ks + i * 16;
            const float uv = u[k];
#pragma unroll
            for (int o = 0; o < 10; ++o) acc[o] += uv * W[o * 500 + k];
        }
        const int k = ks + 496;
        if (k < 500) {
            const float uv = u[k];
#pragma unroll
            for (int o = 0; o < 10; ++o) acc[o] += uv * W[o * 500 + k];
        }
    }
#pragma unroll
    for (int o = 0; o < 10; ++o) red[(il * 10 + o) * 17 + ks] = acc[o];
    __syncthreads();
    if (t < 160) {
        const int il2 = t / 10, o = t - il2 * 10;
        float s = 0.f;
#pragma unroll
        for (int q = 0; q < 16; ++q) s += red[(il2 * 10 + o) * 17 + q];
        out[(size_t)(blk * 16 + il2) * 10 + o] = s + bias[o];
    }
}

__device__ void role_lin500(char* smem, int b,
    const float* __restrict__ f3, const float* __restrict__ w,
    const float* __restrict__ bias, float* __restrict__ u3)
{
    float* fs = (float*)smem;   // 50
    const int t = threadIdx.x;
    if (t < 50) fs[t] = f3[(size_t)b * 50 + t];
    __syncthreads();
    for (int o = t; o < 500; o += 256) {
        float s = 0.f;
#pragma unroll
        for (int k = 0; k < 50; ++k) s += fs[k] * w[o * 50 + k];
        u3[(size_t)b * 512 + o] = fmaxf(s + bias[o], 0.f);
    }
}

// ============================ fused kernels ================================

__global__ __launch_bounds__(256) void k_prep(
    const float* x, const float* c1w, const float* c1b, float* h1,
    const float* l1c1w, bf16_t* Wb1, const float* l1c2w, bf16_t* Wb2,
    const float* c2w, float* w2p)
{
    extern __shared__ char smem[];
    const int g = blockIdx.x;
    if (g < 2704)        role_conv1(smem, g, x, c1w, c1b, h1);
    else if (g < 19664)  role_wb16(g - 2704, l1c1w, Wb1, 500, 8450, 8480, 512 * 8480);
    else if (g < 22224)  role_wb16(g - 19664, l1c2w, Wb2, 500, 1250, 1280, 512 * 1280);
    else                 role_w2t(g - 22224, c2w, w2p);
}

__global__ __launch_bounds__(256) void k_stage1(
    const float* h1, const bf16_t* Wb1, const float* l1c1b, float* u, float* up,
    const float* d1w, const float* d1b, int* e1,
    const float* w2p, const float* c2b, float* h2)
{
    extern __shared__ char smem[];
    const int g = blockIdx.x;
    if (g < 512)         role_gemm(smem, g, h1, 8480, Wb1, l1c1b, u, up, 8480, 4256, 500, 512);
    else if (g < 4608)   role_conv2(smem, g - 512, h1, w2p, c2b, h2);
    else                 role_exit(smem, g - 4608, h1, 8480, 8450, d1w, d1b, e1);
}

__global__ __launch_bounds__(256) void k_stage2(
    const float* h2, const bf16_t* Wb2, const float* l1c2b, float* v, float* vp,
    const float* d2w, const float* d2b, int* e2,
    const float* c3w, const float* c3b, float* f3,
    const float* u, const float* up, const float* l2c1w, const float* l2c1b, float* out1)
{
    extern __shared__ char smem[];
    const int g = blockIdx.x;
    if (g < 512)         role_gemm(smem, g, h2, 1280, Wb2, l1c2b, v, vp, 1280, 640, 500, 512);
    else if (g < 1536)   role_conv3(smem, g - 512, h2, c3w, c3b, f3);
    else if (g < 1792)   role_lin10(smem, g - 1536, u, up, 512, l2c1w, l2c1b, out1);
    else                 role_exit(smem, g - 1792, h2, 1280, 1250, d2w, d2b, e2);
}

__global__ __launch_bounds__(256) void k_stage3a(
    const float* v, const float* vp, const float* l2c2w, const float* l2c2b, float* out2,
    const float* f3, const float* l1w, const float* l1b, float* u3)
{
    extern __shared__ char smem[];
    const int g = blockIdx.x;
    if (g < 256)         role_lin10(smem, g, v, vp, 512, l2c2w, l2c2b, out2);
    else                 role_lin500(smem, g - 256, f3, l1w, l1b, u3);
}

__global__ __launch_bounds__(256) void k_stage3b(
    const float* u3, const float* l2w, const float* l2b, float* out3)
{
    extern __shared__ char smem[];
    role_lin10(smem, blockIdx.x, u3, nullptr, 512, l2w, l2b, out3);
}

__global__ __launch_bounds__(256) void final_select(
    const int* __restrict__ e1, const int* __restrict__ e2,
    const float* __restrict__ o1, const float* __restrict__ o2,
    const float* __restrict__ o3, float* __restrict__ out)
{
    const int b = blockIdx.x * 256 + threadIdx.x;
    if (b >= B_IMG) return;
    const float* src = e1[b] ? o1 : (e2[b] ? o2 : o3);
    src += (size_t)b * 10;
    float v[10];
    float m = -3.4e38f;
#pragma unroll
    for (int o = 0; o < 10; ++o) { v[o] = src[o]; m = fmaxf(m, v[o]); }
    float s = 0.f;
#pragma unroll
    for (int o = 0; o < 10; ++o) s += expf(v[o] - m);
    const float ls = logf(s);
#pragma unroll
    for (int o = 0; o < 10; ++o) out[(size_t)b * 10 + o] = v[o] - m - ls;
}

// ---------------------------------------------------------------------------
static inline size_t align256(size_t v) { return (v + 255) & ~(size_t)255; }

extern "C" void kernel_launch(void* const* d_in, const int* in_sizes, int n_in,
                              void* d_out, int out_size, void* d_ws, size_t ws_size,
                              hipStream_t stream)
{
    const float* x     = (const float*)d_in[0];
    const float* c1w   = (const float*)d_in[1];
    const float* c1b   = (const float*)d_in[2];
    const float* c2w   = (const float*)d_in[3];
    const float* c2b   = (const float*)d_in[4];
    const float* c3w   = (const float*)d_in[5];
    const float* c3b   = (const float*)d_in[6];
    const float* l1c1w = (const float*)d_in[7];
    const float* l1c1b = (const float*)d_in[8];
    const float* l2c1w = (const float*)d_in[9];
    const float* l2c1b = (const float*)d_in[10];
    const float* l1c2w = (const float*)d_in[11];
    const float* l1c2b = (const float*)d_in[12];
    const float* l2c2w = (const float*)d_in[13];
    const float* l2c2b = (const float*)d_in[14];
    const float* l1w   = (const float*)d_in[15];
    const float* l1b   = (const float*)d_in[16];
    const float* l2w   = (const float*)d_in[17];
    const float* l2b   = (const float*)d_in[18];
    const float* d1w   = (const float*)d_in[19];
    const float* d1b   = (const float*)d_in[20];
    const float* d2w   = (const float*)d_in[21];
    const float* d2b   = (const float*)d_in[22];

    // ---- workspace layout (single chunk, B=4096; ~189 MB, fits r9-proven) --
    size_t off = 0;
    const size_t oWb1  = off; off = align256(off + (size_t)512 * 8480 * 2);
    const size_t oWb2  = off; off = align256(off + (size_t)512 * 1280 * 2);
    const size_t oW2P  = off; off = align256(off + (size_t)50 * 600 * 4);
    const size_t oOut1 = off; off = align256(off + (size_t)B_IMG * 10 * 4);
    const size_t oOut2 = off; off = align256(off + (size_t)B_IMG * 10 * 4);
    const size_t oOut3 = off; off = align256(off + (size_t)B_IMG * 10 * 4);
    const size_t oE1   = off; off = align256(off + (size_t)B_IMG * 4);
    const size_t oE2   = off; off = align256(off + (size_t)B_IMG * 4);
    const size_t oH1   = off; off = align256(off + (size_t)B_IMG * 8480 * 4);
    const size_t oH2   = off; off = align256(off + (size_t)B_IMG * 1280 * 4);
    const size_t oU    = off; off = align256(off + (size_t)B_IMG * 512 * 4);
    const size_t oUP   = off; off = align256(off + (size_t)B_IMG * 512 * 4);
    const size_t oF3   = off; off = align256(off + (size_t)B_IMG * 50 * 4);

    char* ws = (char*)d_ws;
    bf16_t* Wb1  = (bf16_t*)(ws + oWb1);
    bf16_t* Wb2  = (bf16_t*)(ws + oWb2);
    float*  w2p  = (float*) (ws + oW2P);
    float*  out1 = (float*) (ws + oOut1);
    float*  out2 = (float*) (ws + oOut2);
    float*  out3 = (float*) (ws + oOut3);
    int*    e1   = (int*)   (ws + oE1);
    int*    e2   = (int*)   (ws + oE2);
    float*  h1   = (float*) (ws + oH1);
    float*  h2   = (float*) (ws + oH2);
    float*  u    = (float*) (ws + oU);
    float*  up   = (float*) (ws + oUP);
    float*  f3   = (float*) (ws + oF3);
    // stage-2/3 scratch carved from the dead h1 region (h1 unused after stage1)
    float*  v    = h1;                          // 4096*512 f32
    float*  vp   = h1 + (size_t)B_IMG * 512;    // 4096*512 f32
    float*  u3   = h1 + (size_t)B_IMG * 1024;   // 4096*512 f32

    float* out = (float*)d_out;

    // P: conv1 + weight conversions (all independent)
    k_prep<<<22342, 256, 2048, stream>>>(x, c1w, c1b, h1, l1c1w, Wb1, l1c2w, Wb2, c2w, w2p);
    // A: gemm1 | conv2 | exit1  (consume h1)
    k_stage1<<<8704, 256, 53248, stream>>>(h1, Wb1, l1c1b, u, up, d1w, d1b, e1, w2p, c2b, h2);
    // C: gemm2 | conv3 | lin10-1 | exit2  (consume h2 / stage1-u)
    k_stage2<<<5888, 256, 20000, stream>>>(h2, Wb2, l1c2b, v, vp, d2w, d2b, e2,
                                           c3w, c3b, f3, u, up, l2c1w, l2c1b, out1);
    // D: lin10-2 | lin500
    k_stage3a<<<4352, 256, 10880, stream>>>(v, vp, l2c2w, l2c2b, out2, f3, l1w, l1b, u3);
    // E: lin10-3
    k_stage3b<<<256, 256, 10880, stream>>>(u3, l2w, l2b, out3);
    // F: select + log_softmax
    final_select<<<B_IMG / 256, 256, 0, stream>>>(e1, e2, out1, out2, out3, out);

    (void)in_sizes; (void)n_in; (void)out_size; (void)ws_size;
}

// Round 11
// 733.518 us; speedup vs baseline: 2.2976x; 1.0099x over previous
//
#include <hip/hip_runtime.h>
#include <hip/hip_bf16.h>
#include <cstdint>

// ---------------------------------------------------------------------------
// ThreeLayerCNN (BranchyNet early-exit), B=4096.
// Precision: conv1/conv2/exit1/exit2 fp32 (argmax parity with numpy ref);
// big FC GEMMs (l1c1, l1c2) bf16 MFMA w/ fp32 accum (output tol 0.146).
// Round 11:
//  - conv2 role: chunked input staging (4-ic, double-buffered) -> LDS
//    24.6 KB -> 6 blocks/CU in fused k_stage1 (was 3). Same FP tree.
//  - k_tail: lin10-2 | lin500 | lin10-3 | select fused per-16-samples
//    (u3/out2/out3 in LDS, never hit HBM). 6 launches -> 4.
// ---------------------------------------------------------------------------

typedef __bf16 bf16_t;
typedef __bf16 bf16x8 __attribute__((ext_vector_type(8)));
typedef float  f32x4  __attribute__((ext_vector_type(4)));

#define B_IMG 4096

// ======================= role bodies (device functions) =====================

__device__ void role_conv1(char* smem, int blk,
    const float* __restrict__ x, const float* __restrict__ w1,
    const float* __restrict__ b1, float* __restrict__ h1)
{
    float* ws = (float*)smem;        // 450
    float* bs = ws + 456;            // 50
    const int t = threadIdx.x;
    for (int i = t; i < 450; i += 256) ws[i] = w1[i];
    if (t < 50) bs[t] = b1[t];
    __syncthreads();

    const int idx = blk * 256 + t;
    if (idx >= B_IMG * 169) return;
    const int b   = idx / 169;
    const int pos = idx % 169;
    const int py = pos / 13, px = pos % 13;

    const float* xp = x + (size_t)b * 784 + (2 * py) * 28 + 2 * px;
    float p[4][4];
#pragma unroll
    for (int r = 0; r < 4; ++r)
#pragma unroll
        for (int c = 0; c < 4; ++c) p[r][c] = xp[r * 28 + c];

    float* hb = h1 + (size_t)b * 8480 + pos;
    if (pos < 30) h1[(size_t)b * 8480 + 8450 + pos] = 0.f;   // zero pad cols

    for (int oc = 0; oc < 50; ++oc) {
        const float* wp = &ws[oc * 9];
        const float w00 = wp[0], w01 = wp[1], w02 = wp[2];
        const float w10 = wp[3], w11 = wp[4], w12 = wp[5];
        const float w20 = wp[6], w21 = wp[7], w22 = wp[8];
        float a[2][2];
#pragma unroll
        for (int dy = 0; dy < 2; ++dy)
#pragma unroll
            for (int dx = 0; dx < 2; ++dx) {
                a[dy][dx] = p[dy + 0][dx + 0] * w00 + p[dy + 0][dx + 1] * w01 + p[dy + 0][dx + 2] * w02
                          + p[dy + 1][dx + 0] * w10 + p[dy + 1][dx + 1] * w11 + p[dy + 1][dx + 2] * w12
                          + p[dy + 2][dx + 0] * w20 + p[dy + 2][dx + 1] * w21 + p[dy + 2][dx + 2] * w22;
            }
        float v = fmaxf(fmaxf(a[0][0], a[0][1]), fmaxf(a[1][0], a[1][1])) + bs[oc];
        hb[oc * 169] = fmaxf(v, 0.f);
    }
}

__device__ void role_wb16(int blk, const float* __restrict__ src,
                          bf16_t* __restrict__ dst, int N, int K, int Kp, int total)
{
    const int idx = blk * 256 + threadIdx.x;
    if (idx >= total) return;
    const int n = idx / Kp, k = idx % Kp;
    const float v = (n < N && k < K) ? src[(size_t)n * K + k] : 0.f;
    dst[idx] = (bf16_t)v;
}

__device__ void role_w2t(int blk, const float* __restrict__ w2, float* __restrict__ w2p)
{
    const int idx = blk * 256 + threadIdx.x;
    if (idx >= 50 * 600) return;
    const int ic = idx / 600, r = idx % 600, oc = r / 12, j = r % 12;
    w2p[idx] = (j < 9) ? w2[oc * 450 + ic * 9 + j] : 0.f;
}

// conv2 (50->50) + relu + pool; block per image, thread = 5 oc x 1 pooled pos.
// LDS: in[2][680] (4-ic input chunks) + wbuf[2][2400] (4-ic weight chunks),
// both double-buffered, one barrier per chunk. Total 24640 B -> 6 blocks/CU.
// FP expression tree identical to r8/r9/r10 (exit2 argmax parity).
__device__ void role_conv2(char* smem, int b,
    const float* __restrict__ h1, const float* __restrict__ w2p,
    const float* __restrict__ b2, float* __restrict__ h2)
{
    float* in   = (float*)smem;          // [2][680]
    float* wbuf = in + 1360;             // [2][2400], 16B-aligned (1360*4=5440)
    const int t = threadIdx.x;

    // stage chunk 0 (ic 0..3): input + weights
    for (int s = t; s < 676; s += 256) in[s] = h1[(size_t)b * 8480 + s];
    {
        const float4* src = (const float4*)w2p;
        float4* dst = (float4*)wbuf;
        for (int s = t; s < 600; s += 256) dst[s] = src[s];
    }
    __syncthreads();
    if (t < 30) h2[(size_t)b * 1280 + 1250 + t] = 0.f;

    const int ocg = t / 25;
    const int pos = t % 25;
    const int py = pos / 5, px = pos % 5;
    const int oc0 = ocg * 5;
    const bool act = (t < 250);

    float acc[5][4];
#pragma unroll
    for (int j = 0; j < 5; ++j)
#pragma unroll
        for (int q = 0; q < 4; ++q) acc[j][q] = 0.f;

    for (int ic0 = 0; ic0 < 50; ic0 += 4) {
        const int cur = (ic0 >> 2) & 1;
        if (ic0 + 4 < 50) {           // prefetch next <=4-ic chunk (input+weights)
            const int nxt = cur ^ 1;
            const int nic2 = (50 - ic0 - 4 < 4) ? (50 - ic0 - 4) : 4;
            for (int s = t; s < nic2 * 169; s += 256)
                in[nxt * 680 + s] = h1[(size_t)b * 8480 + (ic0 + 4) * 169 + s];
            const float4* src = (const float4*)(w2p + (size_t)(ic0 + 4) * 600);
            float4* dst = (float4*)(wbuf + nxt * 2400);
            for (int s = t; s < nic2 * 150; s += 256) dst[s] = src[s];
        }
        if (act) {
            const int nic = (50 - ic0 < 4) ? (50 - ic0) : 4;
            const float* ibc = in + cur * 680 + (2 * py) * 13 + 2 * px;
            for (int icl = 0; icl < nic; ++icl) {
                float p[4][4];
                const float* ip = ibc + icl * 169;
#pragma unroll
                for (int r = 0; r < 4; ++r)
#pragma unroll
                    for (int c = 0; c < 4; ++c) p[r][c] = ip[r * 13 + c];
                const float* wl = wbuf + cur * 2400 + icl * 600 + oc0 * 12;
#pragma unroll
                for (int j = 0; j < 5; ++j) {
                    const f32x4 wv0 = *(const f32x4*)(wl + j * 12);
                    const f32x4 wv1 = *(const f32x4*)(wl + j * 12 + 4);
                    const f32x4 wv2 = *(const f32x4*)(wl + j * 12 + 8);
                    const float w00 = wv0[0], w01 = wv0[1], w02 = wv0[2];
                    const float w10 = wv0[3], w11 = wv1[0], w12 = wv1[1];
                    const float w20 = wv1[2], w21 = wv1[3], w22 = wv2[0];
#pragma unroll
                    for (int dy = 0; dy < 2; ++dy)
#pragma unroll
                        for (int dx = 0; dx < 2; ++dx) {
                            acc[j][dy * 2 + dx] +=
                                  p[dy + 0][dx + 0] * w00 + p[dy + 0][dx + 1] * w01 + p[dy + 0][dx + 2] * w02
                                + p[dy + 1][dx + 0] * w10 + p[dy + 1][dx + 1] * w11 + p[dy + 1][dx + 2] * w12
                                + p[dy + 2][dx + 0] * w20 + p[dy + 2][dx + 1] * w21 + p[dy + 2][dx + 2] * w22;
                        }
                }
            }
        }
        __syncthreads();
    }

    if (act) {
#pragma unroll
        for (int j = 0; j < 5; ++j) {
            float v = fmaxf(fmaxf(acc[j][0], acc[j][1]), fmaxf(acc[j][2], acc[j][3]));
            h2[(size_t)b * 1280 + (oc0 + j) * 25 + pos] = fmaxf(v + b2[oc0 + j], 0.f);
        }
    }
}

__device__ void role_conv3(char* smem, int blk,
    const float* __restrict__ h2, const float* __restrict__ w3,
    const float* __restrict__ b3, float* __restrict__ f3)
{
    float* in = (float*)smem;    // 5000
    const int t = threadIdx.x;
    for (int i = t; i < 5000; i += 256) {
        const int img = i / 1250, off = i % 1250;
        in[i] = h2[(size_t)(blk * 4 + img) * 1280 + off];
    }
    __syncthreads();
    const int il = t >> 6;
    const int oc = t & 63;
    if (oc >= 50) return;

    const float* ip0 = &in[il * 1250];
    float a00 = 0.f, a01 = 0.f, a10 = 0.f, a11 = 0.f;
    for (int ic = 0; ic < 50; ++ic) {
        float p[4][4];
        const float* ip = ip0 + ic * 25;
#pragma unroll
        for (int r = 0; r < 4; ++r)
#pragma unroll
            for (int c = 0; c < 4; ++c) p[r][c] = ip[r * 5 + c];
        const float* wp = &w3[((size_t)oc * 50 + ic) * 9];
        const float w00 = wp[0], w01 = wp[1], w02 = wp[2];
        const float w10 = wp[3], w11 = wp[4], w12 = wp[5];
        const float w20 = wp[6], w21 = wp[7], w22 = wp[8];
        a00 += p[0][0]*w00 + p[0][1]*w01 + p[0][2]*w02 + p[1][0]*w10 + p[1][1]*w11 + p[1][2]*w12 + p[2][0]*w20 + p[2][1]*w21 + p[2][2]*w22;
        a01 += p[0][1]*w00 + p[0][2]*w01 + p[0][3]*w02 + p[1][1]*w10 + p[1][2]*w11 + p[1][3]*w12 + p[2][1]*w20 + p[2][2]*w21 + p[2][3]*w22;
        a10 += p[1][0]*w00 + p[1][1]*w01 + p[1][2]*w02 + p[2][0]*w10 + p[2][1]*w11 + p[2][2]*w12 + p[3][0]*w20 + p[3][1]*w21 + p[3][2]*w22;
        a11 += p[1][1]*w00 + p[1][2]*w01 + p[1][3]*w02 + p[2][1]*w10 + p[2][2]*w11 + p[2][3]*w12 + p[3][1]*w20 + p[3][2]*w21 + p[3][3]*w22;
    }
    float v = fmaxf(fmaxf(a00, a01), fmaxf(a10, a11)) + b3[oc];
    f3[(size_t)(blk * 4 + il) * 50 + oc] = fmaxf(v, 0.f);
}

__device__ void role_exit(char* smem, int b,
    const float* __restrict__ F, int ldf, int K,
    const float* __restrict__ dw, const float* __restrict__ db, int* __restrict__ e)
{
    float* r0 = (float*)smem;   // 256
    float* r1 = r0 + 256;       // 256
    const int t = threadIdx.x;
    const float* f = F + (size_t)b * ldf;
    float s0 = 0.f, s1 = 0.f;
    for (int i = t; i < K; i += 256) {
        const float v = f[i];
        s0 += v * dw[i];
        s1 += v * dw[K + i];
    }
    r0[t] = s0; r1[t] = s1;
    __syncthreads();
    for (int s = 128; s > 0; s >>= 1) {
        if (t < s) { r0[t] += r0[t + s]; r1[t] += r1[t + s]; }
        __syncthreads();
    }
    if (t == 0) e[b] = (r0[0] + db[0] >= r1[0] + db[1]) ? 1 : 0;
}

// MFMA GEMM split-K=2 (r9-proven). g in [0,512): bx=g&31, by=(g>>5)&7, kz=g>>8.
__device__ void role_gemm(char* smem, int g,
    const float* __restrict__ A, int lda, const bf16_t* __restrict__ W,
    const float* __restrict__ bias, float* __restrict__ C0, float* __restrict__ C1,
    int Kp, int khalf, int Nout, int ldc)
{
    bf16_t* As = (bf16_t*)smem;      // 128*40
    bf16_t* Bs = As + 128 * 40;      // 64*40

    const int t = threadIdx.x;
    const int m0 = (g & 31) * 128;
    const int n0 = ((g >> 5) & 7) * 64;
    const int kz = g >> 8;
    const int kbeg = kz ? khalf : 0;
    const int kend = kz ? Kp : khalf;
    float* C = kz ? C1 : C0;

    const int wave = t >> 6;
    const int lane = t & 63;
    const int wm = (wave >> 1) * 64;
    const int wn = (wave & 1) * 32;
    const int quad = lane >> 4;
    const int lr = lane & 15;

    f32x4 acc[4][2];
#pragma unroll
    for (int i = 0; i < 4; ++i)
#pragma unroll
        for (int j = 0; j < 2; ++j) acc[i][j] = (f32x4)0.f;

    const int ar = t >> 2;
    const int ac = (t & 3) * 8;

    for (int k0 = kbeg; k0 < kend; k0 += 32) {
        __syncthreads();
#pragma unroll
        for (int h = 0; h < 2; ++h) {
            const float* ap = A + (size_t)(m0 + ar + h * 64) * lda + k0 + ac;
            const float4 f0 = *(const float4*)ap;
            const float4 f1 = *(const float4*)(ap + 4);
            bf16x8 v;
            v[0] = (bf16_t)f0.x; v[1] = (bf16_t)f0.y; v[2] = (bf16_t)f0.z; v[3] = (bf16_t)f0.w;
            v[4] = (bf16_t)f1.x; v[5] = (bf16_t)f1.y; v[6] = (bf16_t)f1.z; v[7] = (bf16_t)f1.w;
            *(bf16x8*)&As[(ar + h * 64) * 40 + ac] = v;
        }
        *(uint4*)&Bs[ar * 40 + ac] = *(const uint4*)&W[(size_t)(n0 + ar) * Kp + k0 + ac];
        __syncthreads();

        bf16x8 af[4], bfr[2];
#pragma unroll
        for (int i = 0; i < 4; ++i)
            af[i] = *(const bf16x8*)&As[(wm + i * 16 + lr) * 40 + quad * 8];
#pragma unroll
        for (int j = 0; j < 2; ++j)
            bfr[j] = *(const bf16x8*)&Bs[(wn + j * 16 + lr) * 40 + quad * 8];
#pragma unroll
        for (int i = 0; i < 4; ++i)
#pragma unroll
            for (int j = 0; j < 2; ++j)
                acc[i][j] = __builtin_amdgcn_mfma_f32_16x16x32_bf16(af[i], bfr[j], acc[i][j], 0, 0, 0);
    }

#pragma unroll
    for (int j = 0; j < 2; ++j) {
        const int n = n0 + wn + j * 16 + lr;
        const float bv = (kz == 0 && n < Nout) ? bias[n] : 0.f;
#pragma unroll
        for (int i = 0; i < 4; ++i) {
            const int mrow = m0 + wm + i * 16 + quad * 4;
#pragma unroll
            for (int r = 0; r < 4; ++r)
                C[(size_t)(mrow + r) * ldc + n] = acc[i][j][r] + bv;
        }
    }
}

// lin10: out[b,o<10] = (U[+U2]) @ W^T + bias; 16 img x 16 k-strips per block.
__device__ void role_lin10(char* smem, int blk,
    const float* __restrict__ U, const float* __restrict__ U2, int ldu,
    const float* __restrict__ W, const float* __restrict__ bias,
    float* __restrict__ out)
{
    float* red = (float*)smem;   // [16][10][17]
    const int t = threadIdx.x;
    const int ks = t & 15;
    const int il = t >> 4;
    const int b  = blk * 16 + il;
    const float* u = U + (size_t)b * ldu;

    float acc[10];
#pragma unroll
    for (int o = 0; o < 10; ++o) acc[o] = 0.f;

    if (U2) {
        const float* u2 = U2 + (size_t)b * ldu;
        for (int i = 0; i < 31; ++i) {
            const int k = ks + i * 16;
            const float uv = u[k] + u2[k];
#pragma unroll
            for (int o = 0; o < 10; ++o) acc[o] += uv * W[o * 500 + k];
        }
        const int k = ks + 496;
        if (k < 500) {
            const float uv = u[k] + u2[k];
#pragma unroll
            for (int o = 0; o < 10; ++o) acc[o] += uv * W[o * 500 + k];
        }
    } else {
        for (int i = 0; i < 31; ++i) {
            const int k = ks + i * 16;
            const float uv = u[k];
#pragma unroll
            for (int o = 0; o < 10; ++o) acc[o] += uv * W[o * 500 + k];
        }
        const int k = ks + 496;
        if (k < 500) {
            const float uv = u[k];
#pragma unroll
            for (int o = 0; o < 10; ++o) acc[o] += uv * W[o * 500 + k];
        }
    }
#pragma unroll
    for (int o = 0; o < 10; ++o) red[(il * 10 + o) * 17 + ks] = acc[o];
    __syncthreads();
    if (t < 160) {
        const int il2 = t / 10, o = t - il2 * 10;
        float s = 0.f;
#pragma unroll
        for (int q = 0; q < 16; ++q) s += red[(il2 * 10 + o) * 17 + q];
        out[(size_t)(blk * 16 + il2) * 10 + o] = s + bias[o];
    }
}

// ============================ fused kernels ================================

__global__ __launch_bounds__(256) void k_prep(
    const float* x, const float* c1w, const float* c1b, float* h1,
    const float* l1c1w, bf16_t* Wb1, const float* l1c2w, bf16_t* Wb2,
    const float* c2w, float* w2p)
{
    extern __shared__ char smem[];
    const int g = blockIdx.x;
    if (g < 2704)        role_conv1(smem, g, x, c1w, c1b, h1);
    else if (g < 19664)  role_wb16(g - 2704, l1c1w, Wb1, 500, 8450, 8480, 512 * 8480);
    else if (g < 22224)  role_wb16(g - 19664, l1c2w, Wb2, 500, 1250, 1280, 512 * 1280);
    else                 role_w2t(g - 22224, c2w, w2p);
}

__global__ __launch_bounds__(256) void k_stage1(
    const float* h1, const bf16_t* Wb1, const float* l1c1b, float* u, float* up,
    const float* d1w, const float* d1b, int* e1,
    const float* w2p, const float* c2b, float* h2)
{
    extern __shared__ char smem[];
    const int g = blockIdx.x;
    if (g < 512)         role_gemm(smem, g, h1, 8480, Wb1, l1c1b, u, up, 8480, 4256, 500, 512);
    else if (g < 4608)   role_conv2(smem, g - 512, h1, w2p, c2b, h2);
    else                 role_exit(smem, g - 4608, h1, 8480, 8450, d1w, d1b, e1);
}

__global__ __launch_bounds__(256) void k_stage2(
    const float* h2, const bf16_t* Wb2, const float* l1c2b, float* v, float* vp,
    const float* d2w, const float* d2b, int* e2,
    const float* c3w, const float* c3b, float* f3,
    const float* u, const float* up, const float* l2c1w, const float* l2c1b, float* out1)
{
    extern __shared__ char smem[];
    const int g = blockIdx.x;
    if (g < 512)         role_gemm(smem, g, h2, 1280, Wb2, l1c2b, v, vp, 1280, 640, 500, 512);
    else if (g < 1536)   role_conv3(smem, g - 512, h2, c3w, c3b, f3);
    else if (g < 1792)   role_lin10(smem, g - 1536, u, up, 512, l2c1w, l2c1b, out1);
    else                 role_exit(smem, g - 1792, h2, 1280, 1250, d2w, d2b, e2);
}

// k_tail: per block = 16 samples. lin10-2 (v/vp) -> o2loc; lin500 -> u3 LDS;
// lin10-3 (u3 LDS) -> o3loc; select + log_softmax -> out. FP per-(b,o)
// expressions identical to round 10's separate kernels.
__global__ __launch_bounds__(256) void k_tail(
    const float* __restrict__ v, const float* __restrict__ vp,
    const float* __restrict__ l2c2w, const float* __restrict__ l2c2b,
    const float* __restrict__ f3, const float* __restrict__ l1w, const float* __restrict__ l1b,
    const float* __restrict__ l2w, const float* __restrict__ l2b,
    const float* __restrict__ out1, const int* __restrict__ e1, const int* __restrict__ e2,
    float* __restrict__ out)
{
    __shared__ float fs[800];        // 16 x 50
    __shared__ float u3loc[8000];    // 16 x 500
    __shared__ float red[2720];      // 16 x 10 x 17
    __shared__ float o2loc[160];
    __shared__ float o3loc[160];

    const int t   = threadIdx.x;
    const int blk = blockIdx.x;
    const int ks  = t & 15;
    const int il  = t >> 4;

    // stage f3 for 16 images
    for (int i = t; i < 800; i += 256) fs[i] = f3[(size_t)blk * 800 + i];
    __syncthreads();

    // lin500 -> u3loc (same per-(b,o) expression as round 10's role_lin500)
    for (int im = 0; im < 16; ++im) {
        for (int o = t; o < 500; o += 256) {
            float s = 0.f;
#pragma unroll
            for (int k = 0; k < 50; ++k) s += fs[im * 50 + k] * l1w[o * 50 + k];
            u3loc[im * 500 + o] = fmaxf(s + l1b[o], 0.f);
        }
    }

    // lin10-2 from v/vp (global, ldu=512)
    {
        const float* uu  = v  + (size_t)(blk * 16 + il) * 512;
        const float* uu2 = vp + (size_t)(blk * 16 + il) * 512;
        float acc[10];
#pragma unroll
        for (int o = 0; o < 10; ++o) acc[o] = 0.f;
        for (int i = 0; i < 31; ++i) {
            const int k = ks + i * 16;
            const float uv = uu[k] + uu2[k];
#pragma unroll
            for (int o = 0; o < 10; ++o) acc[o] += uv * l2c2w[o * 500 + k];
        }
        const int k = ks + 496;
        if (k < 500) {
            const float uv = uu[k] + uu2[k];
#pragma unroll
            for (int o = 0; o < 10; ++o) acc[o] += uv * l2c2w[o * 500 + k];
        }
        __syncthreads();   // u3loc writes done; red free to use
#pragma unroll
        for (int o = 0; o < 10; ++o) red[(il * 10 + o) * 17 + ks] = acc[o];
        __syncthreads();
        if (t < 160) {
            const int il2 = t / 10, o = t - il2 * 10;
            float s = 0.f;
#pragma unroll
            for (int q = 0; q < 16; ++q) s += red[(il2 * 10 + o) * 17 + q];
            o2loc[t] = s + l2c2b[o];
        }
        __syncthreads();
    }

    // lin10-3 from u3loc (LDS, ldu=500)
    {
        const float* uu = u3loc + il * 500;
        float acc[10];
#pragma unroll
        for (int o = 0; o < 10; ++o) acc[o] = 0.f;
        for (int i = 0; i < 31; ++i) {
            const int k = ks + i * 16;
            const float uv = uu[k];
#pragma unroll
            for (int o = 0; o < 10; ++o) acc[o] += uv * l2w[o * 500 + k];
        }
        const int k = ks + 496;
        if (k < 500) {
            const float uv = uu[k];
#pragma unroll
            for (int o = 0; o < 10; ++o) acc[o] += uv * l2w[o * 500 + k];
        }
#pragma unroll
        for (int o = 0; o < 10; ++o) red[(il * 10 + o) * 17 + ks] = acc[o];
        __syncthreads();
        if (t < 160) {
            const int il2 = t / 10, o = t - il2 * 10;
            float s = 0.f;
#pragma unroll
            for (int q = 0; q < 16; ++q) s += red[(il2 * 10 + o) * 17 + q];
            o3loc[t] = s + l2b[o];
        }
        __syncthreads();
    }

    // select + log_softmax (one thread per sample)
    if (t < 16) {
        const int b = blk * 16 + t;
        float vv[10];
        if (e1[b]) {
            const float* src = out1 + (size_t)b * 10;
#pragma unroll
            for (int o = 0; o < 10; ++o) vv[o] = src[o];
        } else if (e2[b]) {
#pragma unroll
            for (int o = 0; o < 10; ++o) vv[o] = o2loc[t * 10 + o];
        } else {
#pragma unroll
            for (int o = 0; o < 10; ++o) vv[o] = o3loc[t * 10 + o];
        }
        float m = -3.4e38f;
#pragma unroll
        for (int o = 0; o < 10; ++o) m = fmaxf(m, vv[o]);
        float s = 0.f;
#pragma unroll
        for (int o = 0; o < 10; ++o) s += expf(vv[o] - m);
        const float ls = logf(s);
#pragma unroll
        for (int o = 0; o < 10; ++o) out[(size_t)b * 10 + o] = vv[o] - m - ls;
    }
}

// ---------------------------------------------------------------------------
static inline size_t align256(size_t v) { return (v + 255) & ~(size_t)255; }

extern "C" void kernel_launch(void* const* d_in, const int* in_sizes, int n_in,
                              void* d_out, int out_size, void* d_ws, size_t ws_size,
                              hipStream_t stream)
{
    const float* x     = (const float*)d_in[0];
    const float* c1w   = (const float*)d_in[1];
    const float* c1b   = (const float*)d_in[2];
    const float* c2w   = (const float*)d_in[3];
    const float* c2b   = (const float*)d_in[4];
    const float* c3w   = (const float*)d_in[5];
    const float* c3b   = (const float*)d_in[6];
    const float* l1c1w = (const float*)d_in[7];
    const float* l1c1b = (const float*)d_in[8];
    const float* l2c1w = (const float*)d_in[9];
    const float* l2c1b = (const float*)d_in[10];
    const float* l1c2w = (const float*)d_in[11];
    const float* l1c2b = (const float*)d_in[12];
    const float* l2c2w = (const float*)d_in[13];
    const float* l2c2b = (const float*)d_in[14];
    const float* l1w   = (const float*)d_in[15];
    const float* l1b   = (const float*)d_in[16];
    const float* l2w   = (const float*)d_in[17];
    const float* l2b   = (const float*)d_in[18];
    const float* d1w   = (const float*)d_in[19];
    const float* d1b   = (const float*)d_in[20];
    const float* d2w   = (const float*)d_in[21];
    const float* d2b   = (const float*)d_in[22];

    // ---- workspace layout (single chunk, B=4096; fits r9/r10-proven budget)
    size_t off = 0;
    const size_t oWb1  = off; off = align256(off + (size_t)512 * 8480 * 2);
    const size_t oWb2  = off; off = align256(off + (size_t)512 * 1280 * 2);
    const size_t oW2P  = off; off = align256(off + (size_t)50 * 600 * 4);
    const size_t oOut1 = off; off = align256(off + (size_t)B_IMG * 10 * 4);
    const size_t oE1   = off; off = align256(off + (size_t)B_IMG * 4);
    const size_t oE2   = off; off = align256(off + (size_t)B_IMG * 4);
    const size_t oH1   = off; off = align256(off + (size_t)B_IMG * 8480 * 4);
    const size_t oH2   = off; off = align256(off + (size_t)B_IMG * 1280 * 4);
    const size_t oU    = off; off = align256(off + (size_t)B_IMG * 512 * 4);
    const size_t oUP   = off; off = align256(off + (size_t)B_IMG * 512 * 4);
    const size_t oF3   = off; off = align256(off + (size_t)B_IMG * 50 * 4);

    char* ws = (char*)d_ws;
    bf16_t* Wb1  = (bf16_t*)(ws + oWb1);
    bf16_t* Wb2  = (bf16_t*)(ws + oWb2);
    float*  w2p  = (float*) (ws + oW2P);
    float*  out1 = (float*) (ws + oOut1);
    int*    e1   = (int*)   (ws + oE1);
    int*    e2   = (int*)   (ws + oE2);
    float*  h1   = (float*) (ws + oH1);
    float*  h2   = (float*) (ws + oH2);
    float*  u    = (float*) (ws + oU);
    float*  up   = (float*) (ws + oUP);
    float*  f3   = (float*) (ws + oF3);
    // stage-2 gemm outputs carved from the dead h1 region
    float*  v    = h1;                          // 4096*512 f32
    float*  vp   = h1 + (size_t)B_IMG * 512;    // 4096*512 f32

    float* out = (float*)d_out;

    // P: conv1 + weight conversions (all independent)
    k_prep<<<22342, 256, 2048, stream>>>(x, c1w, c1b, h1, l1c1w, Wb1, l1c2w, Wb2, c2w, w2p);
    // A: gemm1 | conv2 | exit1  (consume h1);  24832 B LDS -> 6 blocks/CU
    k_stage1<<<8704, 256, 24832, stream>>>(h1, Wb1, l1c1b, u, up, d1w, d1b, e1, w2p, c2b, h2);
    // C: gemm2 | conv3 | lin10-1 | exit2  (consume h2 / stage1-u)
    k_stage2<<<5888, 256, 20000, stream>>>(h2, Wb2, l1c2b, v, vp, d2w, d2b, e2,
                                           c3w, c3b, f3, u, up, l2c1w, l2c1b, out1);
    // T: lin10-2 | lin500 | lin10-3 | select  (per-16-sample blocks)
    k_tail<<<256, 256, 0, stream>>>(v, vp, l2c2w, l2c2b, f3, l1w, l1b, l2w, l2b,
                                    out1, e1, e2, out);

    (void)in_sizes; (void)n_in; (void)out_size; (void)ws_size;
}